// Round 1
// baseline (1503.886 us; speedup 1.0000x reference)
//
#include <hip/hip_runtime.h>
#include <stdint.h>

#define NHEADS 16
#define DIM 512
#define BWIN 4096
#define NTOK 49
#define M_TOTAL (BWIN * NTOK)          // 200704
#define QSCALE 0.17677669529663687f    // 32^-0.5

typedef __attribute__((ext_vector_type(4))) float  f32x4;
typedef __attribute__((ext_vector_type(8))) short  s16x8;
typedef __attribute__((ext_vector_type(4))) short  s16x4;

__device__ __forceinline__ f32x4 mfma16(s16x8 a, s16x8 b, f32x4 c) {
    return __builtin_amdgcn_mfma_f32_16x16x32_bf16(a, b, c, 0, 0, 0);
}

// f32 -> bf16 round-nearest-even
__device__ __forceinline__ short f2bf(float f) {
    unsigned u = __builtin_bit_cast(unsigned, f);
    u += 0x7FFFu + ((u >> 16) & 1u);
    return (short)(u >> 16);
}

__device__ __forceinline__ void gload16(const void* g, void* l) {
    __builtin_amdgcn_global_load_lds(
        (const __attribute__((address_space(1))) void*)g,
        (__attribute__((address_space(3))) void*)l, 16, 0, 0);
}

// ---------------- prep kernels ----------------

__global__ void k_prep_x(const float* __restrict__ x, short* __restrict__ xb) {
    int i = blockIdx.x * blockDim.x + threadIdx.x;
    int stride = gridDim.x * blockDim.x;
    const int n4 = M_TOTAL * DIM / 4;
    for (; i < n4; i += stride) {
        f32x4 v = ((const f32x4*)x)[i];
        s16x4 o;
        o[0] = f2bf(v[0]); o[1] = f2bf(v[1]); o[2] = f2bf(v[2]); o[3] = f2bf(v[3]);
        ((s16x4*)xb)[i] = o;
    }
}

__global__ void k_prep_w(const float* __restrict__ src, short* __restrict__ dst,
                         int n, int scale_lim) {
    int i = blockIdx.x * blockDim.x + threadIdx.x;
    int stride = gridDim.x * blockDim.x;
    for (; i < n; i += stride) {
        float v = src[i];
        if (i < scale_lim) v *= QSCALE;
        dst[i] = f2bf(v);
    }
}

// bm[w64][h][i*49+j] = bias_table[rel(i,j)*16+h] + mask[w64][i*49+j]
__global__ void k_prep_bm(const float* __restrict__ btab, const float* __restrict__ mask,
                          float* __restrict__ bm) {
    int i = blockIdx.x * blockDim.x + threadIdx.x;
    int stride = gridDim.x * blockDim.x;
    const int n = 64 * NHEADS * NTOK * NTOK;
    for (; i < n; i += stride) {
        int ij  = i % 2401;
        int wh  = i / 2401;
        int h   = wh & 15;
        int w64 = wh >> 4;
        int ti = ij / 49, tj = ij % 49;
        int ridx = (ti / 7 - tj / 7 + 6) * 13 + (ti % 7 - tj % 7 + 6);
        bm[i] = btab[ridx * 16 + h] + mask[w64 * 2401 + ij];
    }
}

// ---------------- GEMM: C[M,N] = A[M,512] @ B^T[N,512] + bias ----------------
// MODE 0: qkv -> bf16 out, stride 1536, bias scaled by QSCALE for n<512
// MODE 1: proj -> f32 out, stride 512
template <int MODE>
__global__ __launch_bounds__(256) void k_gemm(
    const short* __restrict__ A, const short* __restrict__ B,
    const float* __restrict__ bias, void* __restrict__ C,
    int ntiles, int nwg) {
    __shared__ short lA[128 * 32];
    __shared__ short lB[128 * 32];
    const int K = 512;

    int bid   = blockIdx.x;
    int chunk = nwg >> 3;                      // nwg % 8 == 0
    int wg    = (bid & 7) * chunk + (bid >> 3);
    int mt = wg / ntiles;
    int nt = wg - mt * ntiles;

    int t = threadIdx.x;
    int lane = t & 63, wid = t >> 6;
    int l15 = lane & 15, g = lane >> 4;
    int wm = (wid >> 1) * 64, wn = (wid & 1) * 64;

    size_t aoff = (size_t)(mt * 128 + (t >> 2)) * K + (t & 3) * 8;
    size_t boff = (size_t)(nt * 128 + (t >> 2)) * K + (t & 3) * 8;
    char* lAb = (char*)lA + wid * 1024;
    char* lBb = (char*)lB + wid * 1024;

    f32x4 acc[4][4] = {};

    for (int k0 = 0; k0 < K; k0 += 32) {
        gload16(A + aoff + k0,          lAb);
        gload16(A + aoff + k0 + 64 * K, lAb + 4096);
        gload16(B + boff + k0,          lBb);
        gload16(B + boff + k0 + 64 * K, lBb + 4096);
        __syncthreads();

        s16x8 af[4], bf[4];
        const short* pa = lA + (wm + l15) * 32 + g * 8;
        const short* pb = lB + (wn + l15) * 32 + g * 8;
#pragma unroll
        for (int i = 0; i < 4; i++) af[i] = *(const s16x8*)(pa + i * 512);
#pragma unroll
        for (int i = 0; i < 4; i++) bf[i] = *(const s16x8*)(pb + i * 512);
#pragma unroll
        for (int i = 0; i < 4; i++)
#pragma unroll
            for (int j = 0; j < 4; j++)
                acc[i][j] = mfma16(af[i], bf[j], acc[i][j]);
        __syncthreads();
    }

    int m_base = mt * 128 + wm + (g << 2);
    int n_base = nt * 128 + wn + l15;
#pragma unroll
    for (int nj = 0; nj < 4; nj++) {
        int n = n_base + nj * 16;
        float bv = bias[n];
        if (MODE == 0 && n < 512) bv *= QSCALE;
#pragma unroll
        for (int mi = 0; mi < 4; mi++) {
#pragma unroll
            for (int r = 0; r < 4; r++) {
                int m = m_base + mi * 16 + r;
                float v = acc[mi][nj][r] + bv;
                if (MODE == 0)
                    ((short*)C)[(size_t)m * 1536 + n] = f2bf(v);
                else
                    ((float*)C)[(size_t)m * 512 + n] = v;
            }
        }
    }
}

// ---------------- attention ----------------
// 1 block / window; 4 waves x 4 heads. qkv [M][1536] bf16 (q|k|v, each h*32+d).
__global__ __launch_bounds__(256) void k_attn(
    const short* __restrict__ qkv, const float* __restrict__ bm,
    short* __restrict__ ao) {
    __shared__ short Plds[4][64 * 72];   // per-wave P tile, stride 72 (conflict-safe)
    __shared__ int   Vlds[4][49 * 17];   // per-wave V tile, stride 34 shorts

    int w = blockIdx.x;
    int lane = threadIdx.x & 63, wid = threadIdx.x >> 6;
    int l15 = lane & 15, g = lane >> 4;
    const float* bmw = bm + (size_t)(w & 63) * NHEADS * 2401;
    short* pl = &Plds[wid][0];
    const short* vl = (const short*)&Vlds[wid][0];

    for (int hh = 0; hh < 4; ++hh) {
        int h = (wid << 2) + hh;

        // q/k fragments: lane holds row (clamped), d = g*8..g*8+7  (K=32 = hd, one step)
        s16x8 qf[4], kf[4];
#pragma unroll
        for (int mi = 0; mi < 4; mi++) {
            int tq = mi * 16 + l15; if (tq > 48) tq = 48;
            const short* base = qkv + (size_t)(w * 49 + tq) * 1536 + h * 32 + g * 8;
            qf[mi] = *(const s16x8*)(base);
            kf[mi] = *(const s16x8*)(base + 512);
        }

        // stage V[49][32] into LDS (stride 34 shorts -> conflict-free col reads)
#pragma unroll
        for (int i = 0; i < 4; i++) {
            int unit = i * 64 + lane;
            if (unit < 196) {
                int tv = unit >> 2, c = unit & 3;
                int4 ld = *(const int4*)(qkv + (size_t)(w * 49 + tv) * 1536 + 1024 + h * 32 + c * 8);
                int* vw = &Vlds[wid][tv * 17 + c * 4];
                vw[0] = ld.x; vw[1] = ld.y; vw[2] = ld.z; vw[3] = ld.w;
            }
        }

        // S = q'k^T
        f32x4 acc[4][4] = {};
#pragma unroll
        for (int mi = 0; mi < 4; mi++)
#pragma unroll
            for (int nj = 0; nj < 4; nj++)
                acc[mi][nj] = mfma16(qf[mi], kf[nj], acc[mi][nj]);

        // + (rel-pos bias + mask); pad cols -> -1e30
        const float* bmh = bmw + h * 2401;
#pragma unroll
        for (int mi = 0; mi < 4; mi++) {
#pragma unroll
            for (int nj = 0; nj < 4; nj++) {
                int j = nj * 16 + l15;
#pragma unroll
                for (int r = 0; r < 4; r++) {
                    int i = mi * 16 + (g << 2) + r;
                    if (j < 49) {
                        if (i < 49) acc[mi][nj][r] += bmh[i * 49 + j];
                    } else {
                        acc[mi][nj][r] = -1e30f;
                    }
                }
            }
        }

        // softmax over j: row lives across 16 lanes (same g) x 4 nj
#pragma unroll
        for (int mi = 0; mi < 4; mi++) {
#pragma unroll
            for (int r = 0; r < 4; r++) {
                float a0 = acc[mi][0][r], a1 = acc[mi][1][r];
                float a2 = acc[mi][2][r], a3 = acc[mi][3][r];
                float mx = fmaxf(fmaxf(a0, a1), fmaxf(a2, a3));
                mx = fmaxf(mx, __shfl_xor(mx, 1));
                mx = fmaxf(mx, __shfl_xor(mx, 2));
                mx = fmaxf(mx, __shfl_xor(mx, 4));
                mx = fmaxf(mx, __shfl_xor(mx, 8));
                float e0 = __expf(a0 - mx), e1 = __expf(a1 - mx);
                float e2 = __expf(a2 - mx), e3 = __expf(a3 - mx);
                float s = e0 + e1 + e2 + e3;
                s += __shfl_xor(s, 1); s += __shfl_xor(s, 2);
                s += __shfl_xor(s, 4); s += __shfl_xor(s, 8);
                float inv = 1.0f / s;
                acc[mi][0][r] = e0 * inv; acc[mi][1][r] = e1 * inv;
                acc[mi][2][r] = e2 * inv; acc[mi][3][r] = e3 * inv;
            }
        }

        // P -> LDS (bf16)
#pragma unroll
        for (int mi = 0; mi < 4; mi++)
#pragma unroll
            for (int nj = 0; nj < 4; nj++)
#pragma unroll
                for (int r = 0; r < 4; r++)
                    pl[(mi * 16 + (g << 2) + r) * 72 + nj * 16 + l15] = f2bf(acc[mi][nj][r]);
        __syncthreads();

        // PA frags: lane holds P row (mi*16+l15), k = j
        s16x8 pa[4][2];
#pragma unroll
        for (int mi = 0; mi < 4; mi++)
#pragma unroll
            for (int kj = 0; kj < 2; kj++)
                pa[mi][kj] = *(const s16x8*)(pl + (mi * 16 + l15) * 72 + kj * 32 + g * 8);

        // V^T frags from LDS: lane-row = d, k = j (clamped; P[j>=49]=0)
        s16x8 vf[2][2];
#pragma unroll
        for (int nd = 0; nd < 2; nd++)
#pragma unroll
            for (int kj = 0; kj < 2; kj++) {
                s16x8 tmp;
#pragma unroll
                for (int e = 0; e < 8; e++) {
                    int j = kj * 32 + g * 8 + e; if (j > 48) j = 48;
                    tmp[e] = vl[j * 34 + nd * 16 + l15];
                }
                vf[nd][kj] = tmp;
            }

        f32x4 o[4][2] = {};
#pragma unroll
        for (int kj = 0; kj < 2; kj++)
#pragma unroll
            for (int mi = 0; mi < 4; mi++)
#pragma unroll
                for (int nd = 0; nd < 2; nd++)
                    o[mi][nd] = mfma16(pa[mi][kj], vf[nd][kj], o[mi][nd]);

#pragma unroll
        for (int mi = 0; mi < 4; mi++) {
#pragma unroll
            for (int r = 0; r < 4; r++) {
                int i = mi * 16 + (g << 2) + r;
                if (i < 49) {
                    short* op = ao + (size_t)(w * 49 + i) * 512 + h * 32 + l15;
#pragma unroll
                    for (int nd = 0; nd < 2; nd++)
                        op[nd * 16] = f2bf(o[mi][nd][r]);
                }
            }
        }
        __syncthreads();
    }
}

// ---------------- launch ----------------

extern "C" void kernel_launch(void* const* d_in, const int* in_sizes, int n_in,
                              void* d_out, int out_size, void* d_ws, size_t ws_size,
                              hipStream_t stream) {
    const float* x     = (const float*)d_in[0];
    const float* mask  = (const float*)d_in[1];
    const float* Wqkv  = (const float*)d_in[2];
    const float* bqkv  = (const float*)d_in[3];
    const float* btab  = (const float*)d_in[4];
    const float* Wproj = (const float*)d_in[5];
    const float* bproj = (const float*)d_in[6];
    float* out = (float*)d_out;

    char* ws = (char*)d_ws;
    size_t off = 0;
    short* xb     = (short*)(ws + off); off += (size_t)M_TOTAL * 512 * 2;   // 205.5 MB (reused as ao)
    short* qkvb   = (short*)(ws + off); off += (size_t)M_TOTAL * 1536 * 2;  // 616.6 MB
    short* Wqkvb  = (short*)(ws + off); off += (size_t)1536 * 512 * 2;
    short* Wprojb = (short*)(ws + off); off += (size_t)512 * 512 * 2;
    float* bm     = (float*)(ws + off); off += (size_t)64 * NHEADS * 2401 * 4;
    short* ao = xb;   // alias: xb is dead after the qkv GEMM

    k_prep_x<<<2048, 256, 0, stream>>>(x, xb);
    k_prep_w<<<1536, 256, 0, stream>>>(Wqkv, Wqkvb, 1536 * 512, 512 * 512);
    k_prep_w<<<512, 256, 0, stream>>>(Wproj, Wprojb, 512 * 512, 0);
    k_prep_bm<<<2048, 256, 0, stream>>>(btab, mask, bm);

    k_gemm<0><<<18816, 256, 0, stream>>>(xb, Wqkvb, bqkv, qkvb, 12, 18816);
    k_attn<<<4096, 256, 0, stream>>>(qkvb, bm, ao);
    k_gemm<1><<<6272, 256, 0, stream>>>(ao, Wprojb, bproj, out, 4, 6272);
}

// Round 3
// 1333.145 us; speedup vs baseline: 1.1281x; 1.1281x over previous
//
#include <hip/hip_runtime.h>
#include <stdint.h>

#define NHEADS 16
#define DIM 512
#define BWIN 4096
#define NTOK 49
#define M_TOTAL (BWIN * NTOK)          // 200704
#define QSCALE 0.17677669529663687f    // 32^-0.5

typedef __attribute__((ext_vector_type(4)))  float f32x4;
typedef __attribute__((ext_vector_type(16))) float f32x16;
typedef __attribute__((ext_vector_type(8)))  short s16x8;
typedef __attribute__((ext_vector_type(4)))  short s16x4;

__device__ __forceinline__ f32x4 mfma16(s16x8 a, s16x8 b, f32x4 c) {
    return __builtin_amdgcn_mfma_f32_16x16x32_bf16(a, b, c, 0, 0, 0);
}
__device__ __forceinline__ f32x16 mfma32(s16x8 a, s16x8 b, f32x16 c) {
    return __builtin_amdgcn_mfma_f32_32x32x16_bf16(a, b, c, 0, 0, 0);
}

// f32 -> bf16 round-nearest-even
__device__ __forceinline__ short f2bf(float f) {
    unsigned u = __builtin_bit_cast(unsigned, f);
    u += 0x7FFFu + ((u >> 16) & 1u);
    return (short)(u >> 16);
}

// pack two f32 -> 2x bf16 in one dword (lo = a, hi = b)
__device__ __forceinline__ unsigned cvtpk(float a, float b) {
    unsigned r;
    asm("v_cvt_pk_bf16_f32 %0, %1, %2" : "=v"(r) : "v"(a), "v"(b));
    return r;
}

__device__ __forceinline__ void gload16(const void* g, void* l) {
    __builtin_amdgcn_global_load_lds(
        (const __attribute__((address_space(1))) void*)g,
        (__attribute__((address_space(3))) void*)l, 16, 0, 0);
}

// ---------------- prep kernels ----------------

__global__ void k_prep_x(const float* __restrict__ x, short* __restrict__ xb) {
    int i = blockIdx.x * blockDim.x + threadIdx.x;
    int stride = gridDim.x * blockDim.x;
    const int n4 = M_TOTAL * DIM / 4;
    for (; i < n4; i += stride) {
        f32x4 v = ((const f32x4*)x)[i];
        s16x4 o;
        o[0] = f2bf(v[0]); o[1] = f2bf(v[1]); o[2] = f2bf(v[2]); o[3] = f2bf(v[3]);
        ((s16x4*)xb)[i] = o;
    }
}

__global__ void k_prep_w(const float* __restrict__ src, short* __restrict__ dst,
                         int n, int scale_lim) {
    int i = blockIdx.x * blockDim.x + threadIdx.x;
    int stride = gridDim.x * blockDim.x;
    for (; i < n; i += stride) {
        float v = src[i];
        if (i < scale_lim) v *= QSCALE;
        dst[i] = f2bf(v);
    }
}

// bmT[w64][h][j][i64] = bias_table[rel(i,j)*16+h] + mask[w64][i*49+j]   (i padded to 64)
__global__ void k_prep_bm(const float* __restrict__ btab, const float* __restrict__ mask,
                          float* __restrict__ bmT) {
    int idx = blockIdx.x * blockDim.x + threadIdx.x;
    int stride = gridDim.x * blockDim.x;
    const int n = 64 * NHEADS * 49 * 64;
    for (; idx < n; idx += stride) {
        int i = idx & 63;
        int rest = idx >> 6;
        int j = rest % 49;
        int wh = rest / 49;
        int head = wh & 15;
        int w64 = wh >> 4;
        float v = 0.f;
        if (i < 49) {
            int ridx = (i / 7 - j / 7 + 6) * 13 + (i % 7 - j % 7 + 6);
            v = btab[ridx * 16 + head] + mask[(w64 * 49 + i) * 49 + j];
        }
        bmT[idx] = v;
    }
}

// ---------------- GEMM: C[M,N] = A[M,512] @ B^T[N,512] + bias ----------------
template <int MODE>
__global__ __launch_bounds__(256) void k_gemm(
    const short* __restrict__ A, const short* __restrict__ B,
    const float* __restrict__ bias, void* __restrict__ C,
    int ntiles, int nwg) {
    __shared__ short lA[128 * 32];
    __shared__ short lB[128 * 32];
    const int K = 512;

    int bid   = blockIdx.x;
    int chunk = nwg >> 3;                      // nwg % 8 == 0
    int wg    = (bid & 7) * chunk + (bid >> 3);
    int mt = wg / ntiles;
    int nt = wg - mt * ntiles;

    int t = threadIdx.x;
    int lane = t & 63, wid = t >> 6;
    int l15 = lane & 15, g = lane >> 4;
    int wm = (wid >> 1) * 64, wn = (wid & 1) * 64;

    size_t aoff = (size_t)(mt * 128 + (t >> 2)) * K + (t & 3) * 8;
    size_t boff = (size_t)(nt * 128 + (t >> 2)) * K + (t & 3) * 8;
    char* lAb = (char*)lA + wid * 1024;
    char* lBb = (char*)lB + wid * 1024;

    f32x4 acc[4][4] = {};

    for (int k0 = 0; k0 < K; k0 += 32) {
        gload16(A + aoff + k0,          lAb);
        gload16(A + aoff + k0 + 64 * K, lAb + 4096);
        gload16(B + boff + k0,          lBb);
        gload16(B + boff + k0 + 64 * K, lBb + 4096);
        __syncthreads();

        s16x8 af[4], bf[4];
        const short* pa = lA + (wm + l15) * 32 + g * 8;
        const short* pb = lB + (wn + l15) * 32 + g * 8;
#pragma unroll
        for (int i = 0; i < 4; i++) af[i] = *(const s16x8*)(pa + i * 512);
#pragma unroll
        for (int i = 0; i < 4; i++) bf[i] = *(const s16x8*)(pb + i * 512);
#pragma unroll
        for (int i = 0; i < 4; i++)
#pragma unroll
            for (int j = 0; j < 4; j++)
                acc[i][j] = mfma16(af[i], bf[j], acc[i][j]);
        __syncthreads();
    }

    int m_base = mt * 128 + wm + (g << 2);
    int n_base = nt * 128 + wn + l15;
#pragma unroll
    for (int nj = 0; nj < 4; nj++) {
        int n = n_base + nj * 16;
        float bv = bias[n];
        if (MODE == 0 && n < 512) bv *= QSCALE;
#pragma unroll
        for (int mi = 0; mi < 4; mi++) {
#pragma unroll
            for (int r = 0; r < 4; r++) {
                int m = m_base + mi * 16 + r;
                float v = acc[mi][nj][r] + bv;
                if (MODE == 0)
                    ((short*)C)[(size_t)m * 1536 + n] = f2bf(v);
                else
                    ((float*)C)[(size_t)m * 512 + n] = v;
            }
        }
    }
}

// ---------------- attention (LDS-free, 32x32 MFMA + shfl P-transpose) --------
// One wave per (window, head). 4 waves/block, grid = 4096*16/4 = 16384.
__global__ __launch_bounds__(256, 4) void k_attn(
    const short* __restrict__ qkv, const float* __restrict__ bmT,
    short* __restrict__ ao) {
    int wid = threadIdx.x >> 6, lane = threadIdx.x & 63;
    int p = blockIdx.x * 4 + wid;
    int w = p >> 4, head = p & 15;
    int l31 = lane & 31, h = lane >> 5;

    const short* base = qkv + (size_t)w * 49 * 1536 + head * 32;

    // q/k fragments for S^T = K @ Q^T  (A = K: row j = l31(+32jt), k = d = 16s+8h+e;
    //                                   B = Q^T: col i = l31(+32it), same k)
    s16x8 qf[2][2], kf[2][2];
#pragma unroll
    for (int t = 0; t < 2; t++) {
        const short* row = base + (size_t)(t * 32 + l31) * 1536;
#pragma unroll
        for (int s = 0; s < 2; s++) {
            qf[t][s] = *(const s16x8*)(row + 16 * s + 8 * h);
            kf[t][s] = *(const s16x8*)(row + 512 + 16 * s + 8 * h);
        }
    }

    // V B-fragments: lane: col d = l31, k-rows j = 16*jc + 8h + e
    // (rows >= 49 hit zeroed pad / next-window data, killed by P=0)
    union U8 { short s[8]; s16x8 v; };
    U8 vf[4];
    const short* vbase = base + 1024 + l31;
#pragma unroll
    for (int jc = 0; jc < 4; jc++)
#pragma unroll
        for (int e = 0; e < 8; e++)
            vf[jc].s[e] = vbase[(size_t)(16 * jc + 8 * h + e) * 1536];

    // S^T tiles: st[jt][it], elem r: j = 32jt + (r&3)+8(r>>2)+4h, i = 32it + l31
    f32x16 st[2][2] = {};
#pragma unroll
    for (int s = 0; s < 2; s++)
#pragma unroll
        for (int jt = 0; jt < 2; jt++)
#pragma unroll
            for (int it = 0; it < 2; it++)
                st[jt][it] = mfma32(kf[jt][s], qf[it][s], st[jt][it]);

    // + (rel-pos bias + mask), padded j -> -1e30. bmT coalesced over i.
    const float* bs = bmT + ((size_t)((w & 63) * NHEADS + head)) * 3136 + l31;
#pragma unroll
    for (int jt = 0; jt < 2; jt++)
#pragma unroll
        for (int it = 0; it < 2; it++)
#pragma unroll
            for (int r = 0; r < 16; r++) {
                int j = 32 * jt + (r & 3) + 8 * (r >> 2) + 4 * h;
                if (j < 49) st[jt][it][r] += bs[j * 64 + 32 * it];
                else        st[jt][it][r] = -1e30f;
            }

    // softmax over j (per column i): 32 in-lane values + cross-half xor32
    float inv[2];
#pragma unroll
    for (int it = 0; it < 2; it++) {
        float mx = -1e30f;
#pragma unroll
        for (int jt = 0; jt < 2; jt++)
#pragma unroll
            for (int r = 0; r < 16; r++) mx = fmaxf(mx, st[jt][it][r]);
        mx = fmaxf(mx, __shfl_xor(mx, 32));
        float sum = 0.f;
#pragma unroll
        for (int jt = 0; jt < 2; jt++)
#pragma unroll
            for (int r = 0; r < 16; r++) {
                float e = __expf(st[jt][it][r] - mx);
                st[jt][it][r] = e;
                sum += e;
            }
        sum += __shfl_xor(sum, 32);
        inv[it] = 1.0f / sum;
    }

    // PV: out[i][d] = sum_j P[i][j] V[j][d]; P A-frags built in-register.
    // Chunk jc needs lane(h) to hold j_cl = 8h+e; in-lane we have j_cl =
    // (q&3)+8(q>>2)+4h (q = r-rb). Cross-half dwords fetched via shfl_xor(32):
    //   h=0 frag = {pk0, pk0b, partner pk0, partner pk0b}  -> j_cl 0..7
    //   h=1 frag = {partner pk1, partner pk1b, pk1, pk1b}  -> j_cl 8..15
    f32x16 oacc[2] = {};
#pragma unroll
    for (int jc = 0; jc < 4; jc++) {
        const int jt = jc >> 1, rb = 8 * (jc & 1);
#pragma unroll
        for (int it = 0; it < 2; it++) {
            float iv = inv[it];
            unsigned pk0  = cvtpk(st[jt][it][rb + 0] * iv, st[jt][it][rb + 1] * iv);
            unsigned pk0b = cvtpk(st[jt][it][rb + 2] * iv, st[jt][it][rb + 3] * iv);
            unsigned pk1  = cvtpk(st[jt][it][rb + 4] * iv, st[jt][it][rb + 5] * iv);
            unsigned pk1b = cvtpk(st[jt][it][rb + 6] * iv, st[jt][it][rb + 7] * iv);
            unsigned o0  = __shfl_xor(pk0, 32);
            unsigned o0b = __shfl_xor(pk0b, 32);
            unsigned o1  = __shfl_xor(pk1, 32);
            unsigned o1b = __shfl_xor(pk1b, 32);
            union { unsigned d[4]; s16x8 v; } pa;
            pa.d[0] = h ? o1  : pk0;
            pa.d[1] = h ? o1b : pk0b;
            pa.d[2] = h ? pk1 : o0;
            pa.d[3] = h ? pk1b : o0b;
            oacc[it] = mfma32(pa.v, vf[jc].v, oacc[it]);
        }
    }

    // store: col d = l31, row i = 32it + 4h + (r&3) + 8(r>>2); 2x64B lines/instr
    short* ob = ao + (size_t)w * 49 * 512 + head * 32 + l31;
#pragma unroll
    for (int it = 0; it < 2; it++)
#pragma unroll
        for (int r = 0; r < 16; r++) {
            int i = 32 * it + 4 * h + (r & 3) + 8 * (r >> 2);
            if (i < 49) ob[(size_t)i * 512] = f2bf(oacc[it][r]);
        }
}

// ---------------- launch ----------------

extern "C" void kernel_launch(void* const* d_in, const int* in_sizes, int n_in,
                              void* d_out, int out_size, void* d_ws, size_t ws_size,
                              hipStream_t stream) {
    const float* x     = (const float*)d_in[0];
    const float* mask  = (const float*)d_in[1];
    const float* Wqkv  = (const float*)d_in[2];
    const float* bqkv  = (const float*)d_in[3];
    const float* btab  = (const float*)d_in[4];
    const float* Wproj = (const float*)d_in[5];
    const float* bproj = (const float*)d_in[6];
    float* out = (float*)d_out;

    char* ws = (char*)d_ws;
    size_t off = 0;
    short* xb     = (short*)(ws + off); off += (size_t)M_TOTAL * 512 * 2;          // reused as ao
    short* qkvb   = (short*)(ws + off); off += (size_t)(M_TOTAL + 64) * 1536 * 2;  // +64 pad rows
    short* Wqkvb  = (short*)(ws + off); off += (size_t)1536 * 512 * 2;
    short* Wprojb = (short*)(ws + off); off += (size_t)512 * 512 * 2;
    float* bmT    = (float*)(ws + off); off += (size_t)64 * NHEADS * 49 * 64 * 4;  // 12.85 MB
    short* ao = xb;   // alias: xb dead after qkv GEMM

    // zero the qkv pad rows (read by attention for j>=49, multiplied by P=0)
    hipMemsetAsync(qkvb + (size_t)M_TOTAL * 1536, 0, (size_t)64 * 1536 * 2, stream);

    k_prep_x<<<2048, 256, 0, stream>>>(x, xb);
    k_prep_w<<<1536, 256, 0, stream>>>(Wqkv, Wqkvb, 1536 * 512, 512 * 512);
    k_prep_w<<<512, 256, 0, stream>>>(Wproj, Wprojb, 512 * 512, 0);
    k_prep_bm<<<2048, 256, 0, stream>>>(btab, mask, bmT);

    k_gemm<0><<<18816, 256, 0, stream>>>(xb, Wqkvb, bqkv, qkvb, 12, 18816);
    k_attn<<<16384, 256, 0, stream>>>(qkvb, bmT, ao);
    k_gemm<1><<<6272, 256, 0, stream>>>(ao, Wprojb, bproj, out, 4, 6272);
}

// Round 4
// 1304.182 us; speedup vs baseline: 1.1531x; 1.0222x over previous
//
#include <hip/hip_runtime.h>
#include <stdint.h>

#define NHEADS 16
#define DIM 512
#define BWIN 4096
#define NTOK 49
#define M_TOTAL (BWIN * NTOK)          // 200704
#define QSCALE 0.17677669529663687f    // 32^-0.5

typedef __attribute__((ext_vector_type(4)))  float f32x4;
typedef __attribute__((ext_vector_type(16))) float f32x16;
typedef __attribute__((ext_vector_type(8)))  short s16x8;
typedef __attribute__((ext_vector_type(4)))  short s16x4;

__device__ __forceinline__ f32x4 mfma16(s16x8 a, s16x8 b, f32x4 c) {
    return __builtin_amdgcn_mfma_f32_16x16x32_bf16(a, b, c, 0, 0, 0);
}
__device__ __forceinline__ f32x16 mfma32(s16x8 a, s16x8 b, f32x16 c) {
    return __builtin_amdgcn_mfma_f32_32x32x16_bf16(a, b, c, 0, 0, 0);
}

// f32 -> bf16 round-nearest-even
__device__ __forceinline__ short f2bf(float f) {
    unsigned u = __builtin_bit_cast(unsigned, f);
    u += 0x7FFFu + ((u >> 16) & 1u);
    return (short)(u >> 16);
}

// pack two f32 -> 2x bf16 in one dword (lo = a, hi = b)
__device__ __forceinline__ unsigned cvtpk(float a, float b) {
    unsigned r;
    asm("v_cvt_pk_bf16_f32 %0, %1, %2" : "=v"(r) : "v"(a), "v"(b));
    return r;
}

__device__ __forceinline__ void gload16(const void* g, void* l) {
    __builtin_amdgcn_global_load_lds(
        (const __attribute__((address_space(1))) void*)g,
        (__attribute__((address_space(3))) void*)l, 16, 0, 0);
}

// ---------------- prep kernels ----------------

__global__ void k_prep_x(const float* __restrict__ x, short* __restrict__ xb) {
    int i = blockIdx.x * blockDim.x + threadIdx.x;
    int stride = gridDim.x * blockDim.x;
    const int n4 = M_TOTAL * DIM / 4;
    for (; i < n4; i += stride) {
        f32x4 v = ((const f32x4*)x)[i];
        s16x4 o;
        o[0] = f2bf(v[0]); o[1] = f2bf(v[1]); o[2] = f2bf(v[2]); o[3] = f2bf(v[3]);
        ((s16x4*)xb)[i] = o;
    }
}

__global__ void k_prep_w(const float* __restrict__ src, short* __restrict__ dst,
                         int n, int scale_lim) {
    int i = blockIdx.x * blockDim.x + threadIdx.x;
    int stride = gridDim.x * blockDim.x;
    for (; i < n; i += stride) {
        float v = src[i];
        if (i < scale_lim) v *= QSCALE;
        dst[i] = f2bf(v);
    }
}

// bmT[w64][h][j][i64] = bias_table[rel(i,j)*16+h] + mask[w64][i*49+j]   (i padded to 64)
__global__ void k_prep_bm(const float* __restrict__ btab, const float* __restrict__ mask,
                          float* __restrict__ bmT) {
    int idx = blockIdx.x * blockDim.x + threadIdx.x;
    int stride = gridDim.x * blockDim.x;
    const int n = 64 * NHEADS * 49 * 64;
    for (; idx < n; idx += stride) {
        int i = idx & 63;
        int rest = idx >> 6;
        int j = rest % 49;
        int wh = rest / 49;
        int head = wh & 15;
        int w64 = wh >> 4;
        float v = 0.f;
        if (i < 49) {
            int ridx = (i / 7 - j / 7 + 6) * 13 + (i % 7 - j % 7 + 6);
            v = btab[ridx * 16 + head] + mask[(w64 * 49 + i) * 49 + j];
        }
        bmT[idx] = v;
    }
}

// ---------------- GEMM: C[M,N] = A[M,512] @ B^T[N,512] + bias ----------------
// BK=64, both-sides XOR swizzle on LDS (source pre-swizzle + swizzled read).
// MODE 0: qkv -> bf16, head-major planes [which][head][MP][32]
// MODE 1: proj -> f32 out, stride 512
template <int MODE>
__global__ __launch_bounds__(256) void k_gemm(
    const short* __restrict__ A, const short* __restrict__ B,
    const float* __restrict__ bias, void* __restrict__ C,
    int ntiles, int nwg) {
    __shared__ short lA[128 * 64];
    __shared__ short lB[128 * 64];
    const int K = 512;
    const size_t MP = M_TOTAL;

    int bid   = blockIdx.x;
    int chunk = nwg >> 3;                      // nwg % 8 == 0
    int wg    = (bid & 7) * chunk + (bid >> 3);
    int mt = wg / ntiles;
    int nt = wg - mt * ntiles;

    int t = threadIdx.x;
    int lane = t & 63, wid = t >> 6;
    int l15 = lane & 15, g = lane >> 4;
    int wm = (wid >> 1) * 64, wn = (wid & 1) * 64;

    // staging: thread t covers row (t>>3), slot (t&7); source chunk pre-swizzled
    int schunk = (t & 7) ^ ((t >> 3) & 7);
    size_t aoff = (size_t)(mt * 128 + (t >> 3)) * K + schunk * 8;
    size_t boff = (size_t)(nt * 128 + (t >> 3)) * K + schunk * 8;
    char* lAb = (char*)lA + wid * 1024;
    char* lBb = (char*)lB + wid * 1024;

    f32x4 acc[4][4] = {};

    for (int k0 = 0; k0 < K; k0 += 64) {
#pragma unroll
        for (int i = 0; i < 4; i++) {
            gload16(A + aoff + k0 + (size_t)i * 32 * K, lAb + i * 4096);
            gload16(B + boff + k0 + (size_t)i * 32 * K, lBb + i * 4096);
        }
        __syncthreads();

        const short* pa = lA + (wm + l15) * 64;
        const short* pb = lB + (wn + l15) * 64;
        const int sw = l15 & 7;
#pragma unroll
        for (int ks = 0; ks < 2; ks++) {
            s16x8 af[4], bf[4];
            const int co = ((ks * 4) ^ 0);
#pragma unroll
            for (int i = 0; i < 4; i++)
                af[i] = *(const s16x8*)(pa + i * 1024 + (((ks * 4 + g) ^ sw) * 8));
#pragma unroll
            for (int i = 0; i < 4; i++)
                bf[i] = *(const s16x8*)(pb + i * 1024 + (((ks * 4 + g) ^ sw) * 8));
#pragma unroll
            for (int i = 0; i < 4; i++)
#pragma unroll
                for (int j = 0; j < 4; j++)
                    acc[i][j] = mfma16(af[i], bf[j], acc[i][j]);
            (void)co;
        }
        __syncthreads();
    }

    int m_base = mt * 128 + wm + (g << 2);
#pragma unroll
    for (int nj = 0; nj < 4; nj++) {
        int nb = nt * 128 + wn + nj * 16;      // 16-aligned; uniform (which, head)
        float bv = bias[nb + l15];
        if (MODE == 0 && nb < 512) bv *= QSCALE;
#pragma unroll
        for (int mi = 0; mi < 4; mi++) {
#pragma unroll
            for (int r = 0; r < 4; r++) {
                int m = m_base + mi * 16 + r;
                float v = acc[mi][nj][r] + bv;
                if (MODE == 0) {
                    int plane = ((nb >> 9) << 4) | ((nb >> 5) & 15);  // which*16+head
                    size_t dst = ((size_t)plane * MP + m) * 32 + (nb & 31) + l15;
                    ((short*)C)[dst] = f2bf(v);
                } else {
                    ((float*)C)[(size_t)m * 512 + nb + l15] = v;
                }
            }
        }
    }
}

// ---------------- attention (LDS-free, 32x32 MFMA + shfl P-transpose) --------
// qkv head-major: [which][head][MP][32]. One wave per (window, head).
__global__ __launch_bounds__(256, 4) void k_attn(
    const short* __restrict__ qkv, const float* __restrict__ bmT,
    short* __restrict__ ao) {
    int wid = threadIdx.x >> 6, lane = threadIdx.x & 63;
    int p = blockIdx.x * 4 + wid;
    int w = p >> 4, head = p & 15;
    int l31 = lane & 31, h = lane >> 5;
    const size_t MP = M_TOTAL;

    const short* qb = qkv + ((size_t)head * MP + w * 49) * 32;
    const short* kb = qb + (size_t)16 * MP * 32;
    const short* vb = qb + (size_t)32 * MP * 32;

    // q/k fragments for S^T = K @ Q^T (A = K: row j; B = Q^T: col i; k = d)
    s16x8 qf[2][2], kf[2][2];
#pragma unroll
    for (int t = 0; t < 2; t++) {
        int row = t * 32 + l31;
#pragma unroll
        for (int s = 0; s < 2; s++) {
            qf[t][s] = *(const s16x8*)(qb + row * 32 + 16 * s + 8 * h);
            kf[t][s] = *(const s16x8*)(kb + row * 32 + 16 * s + 8 * h);
        }
    }

    // V B-fragments: lane: col d = l31, k-rows j = 16*jc + 8h + e
    // (rows >= 49 read bounded neighbor data, killed by P=0)
    union U8 { short s[8]; s16x8 v; };
    U8 vf[4];
#pragma unroll
    for (int jc = 0; jc < 4; jc++)
#pragma unroll
        for (int e = 0; e < 8; e++)
            vf[jc].s[e] = vb[(16 * jc + 8 * h + e) * 32 + l31];

    // S^T tiles: st[jt][it], elem r: j = 32jt + (r&3)+8(r>>2)+4h, i = 32it + l31
    f32x16 st[2][2] = {};
#pragma unroll
    for (int s = 0; s < 2; s++)
#pragma unroll
        for (int jt = 0; jt < 2; jt++)
#pragma unroll
            for (int it = 0; it < 2; it++)
                st[jt][it] = mfma32(kf[jt][s], qf[it][s], st[jt][it]);

    // + (rel-pos bias + mask), padded j -> -1e30. bmT coalesced over i.
    const float* bs = bmT + ((size_t)((w & 63) * NHEADS + head)) * 3136 + l31;
#pragma unroll
    for (int jt = 0; jt < 2; jt++)
#pragma unroll
        for (int it = 0; it < 2; it++)
#pragma unroll
            for (int r = 0; r < 16; r++) {
                int j = 32 * jt + (r & 3) + 8 * (r >> 2) + 4 * h;
                if (j < 49) st[jt][it][r] += bs[j * 64 + 32 * it];
                else        st[jt][it][r] = -1e30f;
            }

    // softmax over j (per column i): 32 in-lane values + cross-half xor32
    float inv[2];
#pragma unroll
    for (int it = 0; it < 2; it++) {
        float mx = -1e30f;
#pragma unroll
        for (int jt = 0; jt < 2; jt++)
#pragma unroll
            for (int r = 0; r < 16; r++) mx = fmaxf(mx, st[jt][it][r]);
        mx = fmaxf(mx, __shfl_xor(mx, 32));
        float sum = 0.f;
#pragma unroll
        for (int jt = 0; jt < 2; jt++)
#pragma unroll
            for (int r = 0; r < 16; r++) {
                float e = __expf(st[jt][it][r] - mx);
                st[jt][it][r] = e;
                sum += e;
            }
        sum += __shfl_xor(sum, 32);
        inv[it] = 1.0f / sum;
    }

    // PV: P A-frags built in-register (cvt_pk + shfl_xor(32) cross-half fetch)
    f32x16 oacc[2] = {};
#pragma unroll
    for (int jc = 0; jc < 4; jc++) {
        const int jt = jc >> 1, rb = 8 * (jc & 1);
#pragma unroll
        for (int it = 0; it < 2; it++) {
            float iv = inv[it];
            unsigned pk0  = cvtpk(st[jt][it][rb + 0] * iv, st[jt][it][rb + 1] * iv);
            unsigned pk0b = cvtpk(st[jt][it][rb + 2] * iv, st[jt][it][rb + 3] * iv);
            unsigned pk1  = cvtpk(st[jt][it][rb + 4] * iv, st[jt][it][rb + 5] * iv);
            unsigned pk1b = cvtpk(st[jt][it][rb + 6] * iv, st[jt][it][rb + 7] * iv);
            unsigned o0  = __shfl_xor(pk0, 32);
            unsigned o0b = __shfl_xor(pk0b, 32);
            unsigned o1  = __shfl_xor(pk1, 32);
            unsigned o1b = __shfl_xor(pk1b, 32);
            union { unsigned d[4]; s16x8 v; } pa;
            pa.d[0] = h ? o1  : pk0;
            pa.d[1] = h ? o1b : pk0b;
            pa.d[2] = h ? pk1 : o0;
            pa.d[3] = h ? pk1b : o0b;
            oacc[it] = mfma32(pa.v, vf[jc].v, oacc[it]);
        }
    }

    // store: col d = l31, row i = 32it + 4h + (r&3) + 8(r>>2)
    short* ob = ao + (size_t)w * 49 * 512 + head * 32 + l31;
#pragma unroll
    for (int it = 0; it < 2; it++)
#pragma unroll
        for (int r = 0; r < 16; r++) {
            int i = 32 * it + 4 * h + (r & 3) + 8 * (r >> 2);
            if (i < 49) ob[(size_t)i * 512] = f2bf(oacc[it][r]);
        }
}

// ---------------- launch ----------------

extern "C" void kernel_launch(void* const* d_in, const int* in_sizes, int n_in,
                              void* d_out, int out_size, void* d_ws, size_t ws_size,
                              hipStream_t stream) {
    const float* x     = (const float*)d_in[0];
    const float* mask  = (const float*)d_in[1];
    const float* Wqkv  = (const float*)d_in[2];
    const float* bqkv  = (const float*)d_in[3];
    const float* btab  = (const float*)d_in[4];
    const float* Wproj = (const float*)d_in[5];
    const float* bproj = (const float*)d_in[6];
    float* out = (float*)d_out;

    char* ws = (char*)d_ws;
    size_t off = 0;
    short* xb     = (short*)(ws + off); off += (size_t)M_TOTAL * 512 * 2;          // reused as ao
    short* qkvb   = (short*)(ws + off); off += (size_t)48 * M_TOTAL * 32 * 2 + 65536;  // head-major + pad
    short* Wqkvb  = (short*)(ws + off); off += (size_t)1536 * 512 * 2;
    short* Wprojb = (short*)(ws + off); off += (size_t)512 * 512 * 2;
    float* bmT    = (float*)(ws + off); off += (size_t)64 * NHEADS * 49 * 64 * 4;  // 12.85 MB
    short* ao = xb;   // alias: xb dead after qkv GEMM

    k_prep_x<<<2048, 256, 0, stream>>>(x, xb);
    k_prep_w<<<1536, 256, 0, stream>>>(Wqkv, Wqkvb, 1536 * 512, 512 * 512);
    k_prep_w<<<512, 256, 0, stream>>>(Wproj, Wprojb, 512 * 512, 0);
    k_prep_bm<<<2048, 256, 0, stream>>>(btab, mask, bmT);

    k_gemm<0><<<18816, 256, 0, stream>>>(xb, Wqkvb, bqkv, qkvb, 12, 18816);
    k_attn<<<16384, 256, 0, stream>>>(qkvb, bmT, ao);
    k_gemm<1><<<6272, 256, 0, stream>>>(ao, Wprojb, bproj, out, 4, 6272);
}

// Round 5
// 1178.174 us; speedup vs baseline: 1.2765x; 1.1070x over previous
//
#include <hip/hip_runtime.h>
#include <stdint.h>

#define NHEADS 16
#define DIM 512
#define BWIN 4096
#define NTOK 49
#define M_TOTAL (BWIN * NTOK)          // 200704 = 784 * 256
#define QSCALE 0.17677669529663687f    // 32^-0.5

typedef __attribute__((ext_vector_type(4)))  float f32x4;
typedef __attribute__((ext_vector_type(16))) float f32x16;
typedef __attribute__((ext_vector_type(8)))  short s16x8;
typedef __attribute__((ext_vector_type(4)))  short s16x4;

__device__ __forceinline__ f32x4 mfma16(s16x8 a, s16x8 b, f32x4 c) {
    return __builtin_amdgcn_mfma_f32_16x16x32_bf16(a, b, c, 0, 0, 0);
}
__device__ __forceinline__ f32x16 mfma32(s16x8 a, s16x8 b, f32x16 c) {
    return __builtin_amdgcn_mfma_f32_32x32x16_bf16(a, b, c, 0, 0, 0);
}

// f32 -> bf16 round-nearest-even
__device__ __forceinline__ short f2bf(float f) {
    unsigned u = __builtin_bit_cast(unsigned, f);
    u += 0x7FFFu + ((u >> 16) & 1u);
    return (short)(u >> 16);
}

// pack two f32 -> 2x bf16 in one dword (lo = a, hi = b)
__device__ __forceinline__ unsigned cvtpk(float a, float b) {
    unsigned r;
    asm("v_cvt_pk_bf16_f32 %0, %1, %2" : "=v"(r) : "v"(a), "v"(b));
    return r;
}

__device__ __forceinline__ void gload16(const void* g, void* l) {
    __builtin_amdgcn_global_load_lds(
        (const __attribute__((address_space(1))) void*)g,
        (__attribute__((address_space(3))) void*)l, 16, 0, 0);
}

// ---------------- prep kernels ----------------

__global__ void k_prep_x(const float* __restrict__ x, short* __restrict__ xb) {
    int i = blockIdx.x * blockDim.x + threadIdx.x;
    int stride = gridDim.x * blockDim.x;
    const int n4 = M_TOTAL * DIM / 4;
    for (; i < n4; i += stride) {
        f32x4 v = ((const f32x4*)x)[i];
        s16x4 o;
        o[0] = f2bf(v[0]); o[1] = f2bf(v[1]); o[2] = f2bf(v[2]); o[3] = f2bf(v[3]);
        ((s16x4*)xb)[i] = o;
    }
}

__global__ void k_prep_w(const float* __restrict__ src, short* __restrict__ dst,
                         int n, int scale_lim) {
    int i = blockIdx.x * blockDim.x + threadIdx.x;
    int stride = gridDim.x * blockDim.x;
    for (; i < n; i += stride) {
        float v = src[i];
        if (i < scale_lim) v *= QSCALE;
        dst[i] = f2bf(v);
    }
}

// bmT[w64][h][j][i64] = bias_table[rel(i,j)*16+h] + mask[w64][i*49+j]   (i padded to 64)
__global__ void k_prep_bm(const float* __restrict__ btab, const float* __restrict__ mask,
                          float* __restrict__ bmT) {
    int idx = blockIdx.x * blockDim.x + threadIdx.x;
    int stride = gridDim.x * blockDim.x;
    const int n = 64 * NHEADS * 49 * 64;
    for (; idx < n; idx += stride) {
        int i = idx & 63;
        int rest = idx >> 6;
        int j = rest % 49;
        int wh = rest / 49;
        int head = wh & 15;
        int w64 = wh >> 4;
        float v = 0.f;
        if (i < 49) {
            int ridx = (i / 7 - j / 7 + 6) * 13 + (i % 7 - j % 7 + 6);
            v = btab[ridx * 16 + head] + mask[(w64 * 49 + i) * 49 + j];
        }
        bmT[idx] = v;
    }
}

// ---------------- GEMM: C[M,N] = A[M,512] @ B^T[N,512] + bias ----------------
// 256x256 tile, BK=64, 8 waves (2Mx4N), dbuf LDS (128 KB), counted vmcnt(8),
// raw s_barrier (no vmcnt(0) drain in the loop), both-sides XOR swizzle.
// MODE 0: qkv -> bf16 head-major planes [n/32][M][32], LDS-transposed epilogue
// MODE 1: proj -> f32 out, stride 512, direct full-line stores
template <int MODE>
__global__ __launch_bounds__(512, 2) void k_gemm(
    const short* __restrict__ A, const short* __restrict__ B,
    const float* __restrict__ bias, void* __restrict__ C,
    int ntiles, int nwg) {
    __shared__ short lA[2][256 * 64];   // 64 KB
    __shared__ short lB[2][256 * 64];   // 64 KB
    const int K = 512;
    const size_t MP = M_TOTAL;

    int bid   = blockIdx.x;
    int chunk = nwg >> 3;                      // nwg % 8 == 0
    int wg    = (bid & 7) * chunk + (bid >> 3);
    int mt = wg / ntiles;
    int nt = wg - mt * ntiles;

    int t = threadIdx.x;
    int lane = t & 63, wid = t >> 6;
    int l15 = lane & 15, g = (lane >> 4) & 3;
    int wr = wid >> 2, wc = wid & 3;           // wave tile: rows wr*128, cols wc*64

    // staging: thread t covers row (t>>3), 16B-slot (t&7); source chunk pre-swizzled
    int srow = t >> 3;                         // 0..63 (+64*i per issue)
    int schunk = (t & 7) ^ (srow & 7);
    const short* aSrc = A + (size_t)(mt * 256 + srow) * K + schunk * 8;
    const short* bSrc = B + (size_t)(nt * 256 + srow) * K + schunk * 8;
    const int dstOff = t * 8;                  // element offset in LDS (+ i*4096)

    f32x4 acc[8][4] = {};

#define STAGE(buf, k0)                                                        \
    _Pragma("unroll")                                                         \
    for (int i = 0; i < 4; i++) {                                             \
        gload16(aSrc + (size_t)i * 64 * K + (k0), &lA[buf][i * 4096 + dstOff]); \
        gload16(bSrc + (size_t)i * 64 * K + (k0), &lB[buf][i * 4096 + dstOff]); \
    }

    STAGE(0, 0)
    for (int kt = 0; kt < 8; ++kt) {
        if (kt < 7) {
            STAGE((kt + 1) & 1, (kt + 1) * 64)
            asm volatile("s_waitcnt vmcnt(8)" ::: "memory");   // tile kt landed; kt+1 in flight
        } else {
            asm volatile("s_waitcnt vmcnt(0)" ::: "memory");
        }
        __builtin_amdgcn_s_barrier();

        const short* pa = &lA[kt & 1][(wr * 128 + l15) * 64];
        const short* pb = &lB[kt & 1][(wc * 64 + l15) * 64];
        const int sw = l15 & 7;
#pragma unroll
        for (int ks = 0; ks < 2; ks++) {
            s16x8 af[8], bf[4];
#pragma unroll
            for (int mi = 0; mi < 8; mi++)
                af[mi] = *(const s16x8*)(pa + mi * 1024 + (((ks * 4 + g) ^ sw) * 8));
#pragma unroll
            for (int nj = 0; nj < 4; nj++)
                bf[nj] = *(const s16x8*)(pb + nj * 1024 + (((ks * 4 + g) ^ sw) * 8));
#pragma unroll
            for (int mi = 0; mi < 8; mi++)
#pragma unroll
                for (int nj = 0; nj < 4; nj++)
                    acc[mi][nj] = mfma16(af[mi], bf[nj], acc[mi][nj]);
        }
        __builtin_amdgcn_s_barrier();   // all waves done reading buf[kt&1]
    }
#undef STAGE

    int m0 = mt * 256 + wr * 128;
    int n0 = nt * 256 + wc * 64;

    if (MODE == 0) {
        // bounce C through dead LDS: per-wave 128x64 bf16 region (16 KB)
        short* region = (wid < 4) ? (&lA[0][0] + wid * 8192)
                                  : (&lB[0][0] + (wid - 4) * 8192);
#pragma unroll
        for (int nj = 0; nj < 4; nj++) {
            int n = n0 + nj * 16 + l15;
            float bv = bias[n];
            if (n < 512) bv *= QSCALE;
            int w16 = nj * 2 + (l15 >> 3);
#pragma unroll
            for (int mi = 0; mi < 8; mi++)
#pragma unroll
                for (int r = 0; r < 4; r++) {
                    int row = mi * 16 + g * 4 + r;
                    region[row * 64 + ((w16 ^ (row & 7)) * 8) + (l15 & 7)] =
                        f2bf(acc[mi][nj][r] + bv);
                }
        }
        // per-wave private region: no barrier needed; lgkm handled by compiler
#pragma unroll
        for (int p = 0; p < 2; p++) {
            int plane = (n0 >> 5) + p;                       // n/32 = which*16+head
            short* dst = (short*)C + ((size_t)plane * MP + m0) * 32;
#pragma unroll
            for (int i = 0; i < 8; i++) {
                int f = i * 64 + lane;
                int row = f >> 2, c = f & 3;
                s16x8 v = *(const s16x8*)(region + row * 64 +
                                          (((p * 4 + c) ^ (row & 7)) * 8));
                *(s16x8*)(dst + (size_t)f * 8) = v;          // fully coalesced 16B
            }
        }
    } else {
#pragma unroll
        for (int nj = 0; nj < 4; nj++) {
            int n = n0 + nj * 16 + l15;
            float bv = bias[n];
#pragma unroll
            for (int mi = 0; mi < 8; mi++)
#pragma unroll
                for (int r = 0; r < 4; r++) {
                    int m = m0 + mi * 16 + g * 4 + r;
                    ((float*)C)[(size_t)m * 512 + n] = acc[mi][nj][r] + bv;
                }
        }
    }
}

// ---------------- attention (LDS-free, 32x32 MFMA + shfl P-transpose) --------
// qkv head-major: [which][head][MP][32]. One wave per (window, head).
__global__ __launch_bounds__(256, 4) void k_attn(
    const short* __restrict__ qkv, const float* __restrict__ bmT,
    short* __restrict__ ao) {
    int wid = threadIdx.x >> 6, lane = threadIdx.x & 63;
    int p = blockIdx.x * 4 + wid;
    int w = p >> 4, head = p & 15;
    int l31 = lane & 31, h = lane >> 5;
    const size_t MP = M_TOTAL;

    const short* qb = qkv + ((size_t)head * MP + w * 49) * 32;
    const short* kb = qb + (size_t)16 * MP * 32;
    const short* vb = qb + (size_t)32 * MP * 32;

    // q/k fragments for S^T = K @ Q^T (A = K: row j; B = Q^T: col i; k = d)
    s16x8 qf[2][2], kf[2][2];
#pragma unroll
    for (int t = 0; t < 2; t++) {
        int row = t * 32 + l31;
#pragma unroll
        for (int s = 0; s < 2; s++) {
            qf[t][s] = *(const s16x8*)(qb + row * 32 + 16 * s + 8 * h);
            kf[t][s] = *(const s16x8*)(kb + row * 32 + 16 * s + 8 * h);
        }
    }

    // V B-fragments: lane: col d = l31, k-rows j = 16*jc + 8h + e
    // (rows >= 49 read bounded neighbor data, killed by P=0)
    union U8 { short s[8]; s16x8 v; };
    U8 vf[4];
#pragma unroll
    for (int jc = 0; jc < 4; jc++)
#pragma unroll
        for (int e = 0; e < 8; e++)
            vf[jc].s[e] = vb[(16 * jc + 8 * h + e) * 32 + l31];

    // S^T tiles: st[jt][it], elem r: j = 32jt + (r&3)+8(r>>2)+4h, i = 32it + l31
    f32x16 st[2][2] = {};
#pragma unroll
    for (int s = 0; s < 2; s++)
#pragma unroll
        for (int jt = 0; jt < 2; jt++)
#pragma unroll
            for (int it = 0; it < 2; it++)
                st[jt][it] = mfma32(kf[jt][s], qf[it][s], st[jt][it]);

    // + (rel-pos bias + mask), padded j -> -1e30. bmT coalesced over i.
    const float* bs = bmT + ((size_t)((w & 63) * NHEADS + head)) * 3136 + l31;
#pragma unroll
    for (int jt = 0; jt < 2; jt++)
#pragma unroll
        for (int it = 0; it < 2; it++)
#pragma unroll
            for (int r = 0; r < 16; r++) {
                int j = 32 * jt + (r & 3) + 8 * (r >> 2) + 4 * h;
                if (j < 49) st[jt][it][r] += bs[j * 64 + 32 * it];
                else        st[jt][it][r] = -1e30f;
            }

    // softmax over j (per column i): 32 in-lane values + cross-half xor32
    float inv[2];
#pragma unroll
    for (int it = 0; it < 2; it++) {
        float mx = -1e30f;
#pragma unroll
        for (int jt = 0; jt < 2; jt++)
#pragma unroll
            for (int r = 0; r < 16; r++) mx = fmaxf(mx, st[jt][it][r]);
        mx = fmaxf(mx, __shfl_xor(mx, 32));
        float sum = 0.f;
#pragma unroll
        for (int jt = 0; jt < 2; jt++)
#pragma unroll
            for (int r = 0; r < 16; r++) {
                float e = __expf(st[jt][it][r] - mx);
                st[jt][it][r] = e;
                sum += e;
            }
        sum += __shfl_xor(sum, 32);
        inv[it] = 1.0f / sum;
    }

    // PV: P A-frags built in-register (cvt_pk + shfl_xor(32) cross-half fetch)
    f32x16 oacc[2] = {};
#pragma unroll
    for (int jc = 0; jc < 4; jc++) {
        const int jt = jc >> 1, rb = 8 * (jc & 1);
#pragma unroll
        for (int it = 0; it < 2; it++) {
            float iv = inv[it];
            unsigned pk0  = cvtpk(st[jt][it][rb + 0] * iv, st[jt][it][rb + 1] * iv);
            unsigned pk0b = cvtpk(st[jt][it][rb + 2] * iv, st[jt][it][rb + 3] * iv);
            unsigned pk1  = cvtpk(st[jt][it][rb + 4] * iv, st[jt][it][rb + 5] * iv);
            unsigned pk1b = cvtpk(st[jt][it][rb + 6] * iv, st[jt][it][rb + 7] * iv);
            unsigned o0  = __shfl_xor(pk0, 32);
            unsigned o0b = __shfl_xor(pk0b, 32);
            unsigned o1  = __shfl_xor(pk1, 32);
            unsigned o1b = __shfl_xor(pk1b, 32);
            union { unsigned d[4]; s16x8 v; } pa;
            pa.d[0] = h ? o1  : pk0;
            pa.d[1] = h ? o1b : pk0b;
            pa.d[2] = h ? pk1 : o0;
            pa.d[3] = h ? pk1b : o0b;
            oacc[it] = mfma32(pa.v, vf[jc].v, oacc[it]);
        }
    }

    // store: col d = l31, row i = 32it + 4h + (r&3) + 8(r>>2)
    short* ob = ao + (size_t)w * 49 * 512 + head * 32 + l31;
#pragma unroll
    for (int it = 0; it < 2; it++)
#pragma unroll
        for (int r = 0; r < 16; r++) {
            int i = 32 * it + 4 * h + (r & 3) + 8 * (r >> 2);
            if (i < 49) ob[(size_t)i * 512] = f2bf(oacc[it][r]);
        }
}

// ---------------- launch ----------------

extern "C" void kernel_launch(void* const* d_in, const int* in_sizes, int n_in,
                              void* d_out, int out_size, void* d_ws, size_t ws_size,
                              hipStream_t stream) {
    const float* x     = (const float*)d_in[0];
    const float* mask  = (const float*)d_in[1];
    const float* Wqkv  = (const float*)d_in[2];
    const float* bqkv  = (const float*)d_in[3];
    const float* btab  = (const float*)d_in[4];
    const float* Wproj = (const float*)d_in[5];
    const float* bproj = (const float*)d_in[6];
    float* out = (float*)d_out;

    char* ws = (char*)d_ws;
    size_t off = 0;
    short* xb     = (short*)(ws + off); off += (size_t)M_TOTAL * 512 * 2;          // reused as ao
    short* qkvb   = (short*)(ws + off); off += (size_t)48 * M_TOTAL * 32 * 2 + 65536;  // head-major + pad
    short* Wqkvb  = (short*)(ws + off); off += (size_t)1536 * 512 * 2;
    short* Wprojb = (short*)(ws + off); off += (size_t)512 * 512 * 2;
    float* bmT    = (float*)(ws + off); off += (size_t)64 * NHEADS * 49 * 64 * 4;  // 12.85 MB
    short* ao = xb;   // alias: xb dead after qkv GEMM

    k_prep_x<<<2048, 256, 0, stream>>>(x, xb);
    k_prep_w<<<1536, 256, 0, stream>>>(Wqkv, Wqkvb, 1536 * 512, 512 * 512);
    k_prep_w<<<512, 256, 0, stream>>>(Wproj, Wprojb, 512 * 512, 0);
    k_prep_bm<<<2048, 256, 0, stream>>>(btab, mask, bmT);

    k_gemm<0><<<4704, 512, 0, stream>>>(xb, Wqkvb, bqkv, qkvb, 6, 4704);
    k_attn<<<16384, 256, 0, stream>>>(qkvb, bmT, ao);
    k_gemm<1><<<1568, 512, 0, stream>>>(ao, Wprojb, bproj, out, 2, 1568);
}

// Round 6
// 1164.177 us; speedup vs baseline: 1.2918x; 1.0120x over previous
//
#include <hip/hip_runtime.h>
#include <stdint.h>

#define NHEADS 16
#define DIM 512
#define BWIN 4096
#define NTOK 49
#define M_TOTAL (BWIN * NTOK)          // 200704 = 784 * 256
#define QSCALE 0.17677669529663687f    // 32^-0.5

typedef __attribute__((ext_vector_type(4)))  float f32x4;
typedef __attribute__((ext_vector_type(16))) float f32x16;
typedef __attribute__((ext_vector_type(8)))  short s16x8;
typedef __attribute__((ext_vector_type(4)))  short s16x4;

__device__ __forceinline__ f32x4 mfma16(s16x8 a, s16x8 b, f32x4 c) {
    return __builtin_amdgcn_mfma_f32_16x16x32_bf16(a, b, c, 0, 0, 0);
}
__device__ __forceinline__ f32x16 mfma32(s16x8 a, s16x8 b, f32x16 c) {
    return __builtin_amdgcn_mfma_f32_32x32x16_bf16(a, b, c, 0, 0, 0);
}

// f32 -> bf16 round-nearest-even
__device__ __forceinline__ short f2bf(float f) {
    unsigned u = __builtin_bit_cast(unsigned, f);
    u += 0x7FFFu + ((u >> 16) & 1u);
    return (short)(u >> 16);
}

// pack two f32 -> 2x bf16 in one dword (lo = a, hi = b)
__device__ __forceinline__ unsigned cvtpk(float a, float b) {
    unsigned r;
    asm("v_cvt_pk_bf16_f32 %0, %1, %2" : "=v"(r) : "v"(a), "v"(b));
    return r;
}

__device__ __forceinline__ void gload16(const void* g, void* l) {
    __builtin_amdgcn_global_load_lds(
        (const __attribute__((address_space(1))) void*)g,
        (__attribute__((address_space(3))) void*)l, 16, 0, 0);
}

// ---------------- prep kernels ----------------

__global__ void k_prep_x(const float* __restrict__ x, short* __restrict__ xb) {
    int i = blockIdx.x * blockDim.x + threadIdx.x;
    int stride = gridDim.x * blockDim.x;
    const int n4 = M_TOTAL * DIM / 4;
    for (; i < n4; i += stride) {
        f32x4 v = ((const f32x4*)x)[i];
        s16x4 o;
        o[0] = f2bf(v[0]); o[1] = f2bf(v[1]); o[2] = f2bf(v[2]); o[3] = f2bf(v[3]);
        ((s16x4*)xb)[i] = o;
    }
}

__global__ void k_prep_w(const float* __restrict__ src, short* __restrict__ dst,
                         int n, int scale_lim) {
    int i = blockIdx.x * blockDim.x + threadIdx.x;
    int stride = gridDim.x * blockDim.x;
    for (; i < n; i += stride) {
        float v = src[i];
        if (i < scale_lim) v *= QSCALE;
        dst[i] = f2bf(v);
    }
}

// bmT[w64][h][j][i64] = bias_table[rel(i,j)*16+h] + mask[w64][i*49+j]   (i padded to 64)
__global__ void k_prep_bm(const float* __restrict__ btab, const float* __restrict__ mask,
                          float* __restrict__ bmT) {
    int idx = blockIdx.x * blockDim.x + threadIdx.x;
    int stride = gridDim.x * blockDim.x;
    const int n = 64 * NHEADS * 49 * 64;
    for (; idx < n; idx += stride) {
        int i = idx & 63;
        int rest = idx >> 6;
        int j = rest % 49;
        int wh = rest / 49;
        int head = wh & 15;
        int w64 = wh >> 4;
        float v = 0.f;
        if (i < 49) {
            int ridx = (i / 7 - j / 7 + 6) * 13 + (i % 7 - j % 7 + 6);
            v = btab[ridx * 16 + head] + mask[(w64 * 49 + i) * 49 + j];
        }
        bmT[idx] = v;
    }
}

// ---------------- GEMM: C[M,N] = A[M,512] @ B^T[N,512] + bias ----------------
// 256x256 tile, BK=64, 8 waves (2Mx4N), 8-phase schedule (T3+T4+T5):
// per phase: {ds_read quadrant frags || stage 1 half-tile} -> vmcnt(4) ->
// s_barrier -> lgkmcnt(0)+sched_barrier -> setprio(1) 16xMFMA setprio(0) ->
// s_barrier. Half-tiles: A split by row bit6, B by row bit5, so each
// quadrant touches exactly one half; stage order {Ah0,Bh0,Bh1,Ah1} vs
// consume order {Q00,Q01,Q11,Q10} gives every load >=3-phase lag, which
// vmcnt(4) (= 2 newest half-tiles outstanding) provably covers.
// MODE 0: qkv -> bf16 head-major planes [n/32][M][32] via LDS-bounce epilogue
// MODE 1: proj -> f32 out, stride 512, direct stores
template <int MODE>
__global__ __launch_bounds__(512, 2) void k_gemm(
    const short* __restrict__ A, const short* __restrict__ B,
    const float* __restrict__ bias, void* __restrict__ C,
    int ntiles, int nwg) {
    __shared__ short lA[2][256 * 64];   // 64 KB
    __shared__ short lB[2][256 * 64];   // 64 KB
    const int K = 512;
    const size_t MP = M_TOTAL;

    int bid   = blockIdx.x;
    int chunk = nwg >> 3;                      // nwg % 8 == 0
    int wg    = (bid & 7) * chunk + (bid >> 3);
    int mt = wg / ntiles;
    int nt = wg - mt * ntiles;

    int t = threadIdx.x;
    int lane = t & 63, wid = t >> 6;
    int l15 = lane & 15, g = (lane >> 4) & 3;
    int wr = wid >> 2, wc = wid & 3;           // wave tile: rows wr*128, cols wc*64

    const short* aT = A + (size_t)mt * 256 * K;
    const short* bT = B + (size_t)nt * 256 * K;

    f32x4 acc[8][4] = {};
    s16x8 af[4][2], bf0[2][2], bf1[2][2];

// stage half-tile (128 rows x 64 K, 2 gloads): A halves by row bit6, B by bit5
#define STAGE_A(buf, H, kt) do {                                               \
    _Pragma("unroll") for (int j = 0; j < 2; j++) {                            \
        int r_ = j * 128 + (H) * 64 + (t >> 3);                                \
        int sc_ = (t & 7) ^ (r_ & 7);                                          \
        gload16(aT + (size_t)r_ * K + (kt) * 64 + sc_ * 8,                     \
                &lA[buf][r_ * 64 + (t & 7) * 8]);                              \
    } } while (0)

#define STAGE_B(buf, H, kt) do {                                               \
    _Pragma("unroll") for (int j = 0; j < 2; j++) {                            \
        int u_ = j * 64 + (t >> 3);                                            \
        int r_ = ((u_ >> 5) << 6) | ((H) << 5) | (u_ & 31);                    \
        int sc_ = (t & 7) ^ (r_ & 7);                                          \
        gload16(bT + (size_t)r_ * K + (kt) * 64 + sc_ * 8,                     \
                &lB[buf][r_ * 64 + (t & 7) * 8]);                              \
    } } while (0)

#define LDA(MH, cur) do {                                                      \
    const short* pa_ = &lA[cur][(wr * 128 + (MH) * 64 + l15) * 64];            \
    _Pragma("unroll") for (int mi = 0; mi < 4; mi++)                           \
    _Pragma("unroll") for (int ks = 0; ks < 2; ks++)                           \
        af[mi][ks] = *(const s16x8*)(pa_ + mi * 1024 +                         \
                                     (((ks * 4 + g) ^ (l15 & 7)) * 8));        \
    } while (0)

#define LDB(BF, NH, cur) do {                                                  \
    const short* pb_ = &lB[cur][(wc * 64 + (NH) * 32 + l15) * 64];             \
    _Pragma("unroll") for (int nj = 0; nj < 2; nj++)                           \
    _Pragma("unroll") for (int ks = 0; ks < 2; ks++)                           \
        BF[nj][ks] = *(const s16x8*)(pb_ + nj * 1024 +                         \
                                     (((ks * 4 + g) ^ (l15 & 7)) * 8));        \
    } while (0)

#define MMQ(BF, MH, NH) do {                                                   \
    __builtin_amdgcn_s_setprio(1);                                             \
    _Pragma("unroll") for (int ks = 0; ks < 2; ks++)                           \
    _Pragma("unroll") for (int mi = 0; mi < 4; mi++)                           \
    _Pragma("unroll") for (int nj = 0; nj < 2; nj++)                           \
        acc[(MH) * 4 + mi][(NH) * 2 + nj] =                                    \
            mfma16(af[mi][ks], BF[nj][ks], acc[(MH) * 4 + mi][(NH) * 2 + nj]); \
    __builtin_amdgcn_s_setprio(0);                                             \
} while (0)

#define BAR() __builtin_amdgcn_s_barrier()
#define LGW() do { asm volatile("s_waitcnt lgkmcnt(0)" ::: "memory");          \
                   __builtin_amdgcn_sched_barrier(0); } while (0)
#define VMW(st) do {                                                           \
    if (st) asm volatile("s_waitcnt vmcnt(4)" ::: "memory");                   \
    else    asm volatile("s_waitcnt vmcnt(0)" ::: "memory"); } while (0)

    // prologue: tile 0, issue order = consumption order
    STAGE_A(0, 0, 0);
    STAGE_B(0, 0, 0);
    STAGE_B(0, 1, 0);
    STAGE_A(0, 1, 0);
    asm volatile("s_waitcnt vmcnt(4)" ::: "memory");   // Ah0,Bh0 landed
    BAR();

    for (int kt = 0; kt < 8; ++kt) {
        const int cur = kt & 1, nxt = cur ^ 1;
        const bool st = kt < 7;
        // phase 1: Q(0,0) = Ah0 x Bh0 ; stage Ah0(kt+1)
        LDA(0, cur); LDB(bf0, 0, cur);
        if (st) STAGE_A(nxt, 0, kt + 1);
        VMW(st); BAR(); LGW();
        MMQ(bf0, 0, 0);
        BAR();
        // phase 2: Q(0,1) = Ah0 x Bh1 ; stage Bh0(kt+1)
        LDB(bf1, 1, cur);
        if (st) STAGE_B(nxt, 0, kt + 1);
        VMW(st); BAR(); LGW();
        MMQ(bf1, 0, 1);
        BAR();
        // phase 3: Q(1,1) = Ah1 x Bh1 ; stage Bh1(kt+1)
        LDA(1, cur);
        if (st) STAGE_B(nxt, 1, kt + 1);
        VMW(st); BAR(); LGW();
        MMQ(bf1, 1, 1);
        BAR();
        // phase 4: Q(1,0) = Ah1 x Bh0 ; stage Ah1(kt+1)
        if (st) STAGE_A(nxt, 1, kt + 1);
        VMW(st); BAR(); LGW();
        MMQ(bf0, 1, 0);
        BAR();
    }

#undef STAGE_A
#undef STAGE_B
#undef LDA
#undef LDB
#undef MMQ
#undef BAR
#undef LGW
#undef VMW

    int m0 = mt * 256 + wr * 128;
    int n0 = nt * 256 + wc * 64;

    if (MODE == 0) {
        // bounce C through dead LDS: per-wave 128x64 bf16 region (16 KB)
        short* region = (wid < 4) ? (&lA[0][0] + wid * 8192)
                                  : (&lB[0][0] + (wid - 4) * 8192);
#pragma unroll
        for (int a = 0; a < 4; a++) {
            int co = (a >> 1) * 32 + (a & 1) * 16;       // col offset of acc[.][a]
            int n = n0 + co + l15;
            float bv = bias[n];
            if (n < 512) bv *= QSCALE;
            int w16 = (co >> 3) + (l15 >> 3);
#pragma unroll
            for (int mi = 0; mi < 8; mi++)
#pragma unroll
                for (int r = 0; r < 4; r++) {
                    int row = mi * 16 + g * 4 + r;
                    region[row * 64 + ((w16 ^ (row & 7)) * 8) + (l15 & 7)] =
                        f2bf(acc[mi][a][r] + bv);
                }
        }
        // per-wave private region; compiler inserts lgkmcnt for RAW
#pragma unroll
        for (int p = 0; p < 2; p++) {
            int plane = (n0 >> 5) + p;                   // n/32 = which*16+head
            short* dst = (short*)C + ((size_t)plane * MP + m0) * 32;
#pragma unroll
            for (int i = 0; i < 8; i++) {
                int f = i * 64 + lane;
                int row = f >> 2, c = f & 3;
                s16x8 v = *(const s16x8*)(region + row * 64 +
                                          (((p * 4 + c) ^ (row & 7)) * 8));
                *(s16x8*)(dst + (size_t)f * 8) = v;      // coalesced 16B
            }
        }
    } else {
#pragma unroll
        for (int a = 0; a < 4; a++) {
            int co = (a >> 1) * 32 + (a & 1) * 16;
            int n = n0 + co + l15;
            float bv = bias[n];
#pragma unroll
            for (int mi = 0; mi < 8; mi++)
#pragma unroll
                for (int r = 0; r < 4; r++) {
                    int m = m0 + mi * 16 + g * 4 + r;
                    ((float*)C)[(size_t)m * 512 + n] = acc[mi][a][r] + bv;
                }
        }
    }
}

// ---------------- attention (LDS-free, 32x32 MFMA + shfl P-transpose) --------
// qkv head-major: [which][head][MP][32]. One wave per (window, head).
__global__ __launch_bounds__(256, 4) void k_attn(
    const short* __restrict__ qkv, const float* __restrict__ bmT,
    short* __restrict__ ao) {
    int wid = threadIdx.x >> 6, lane = threadIdx.x & 63;
    int p = blockIdx.x * 4 + wid;
    int w = p >> 4, head = p & 15;
    int l31 = lane & 31, h = lane >> 5;
    const size_t MP = M_TOTAL;

    const short* qb = qkv + ((size_t)head * MP + w * 49) * 32;
    const short* kb = qb + (size_t)16 * MP * 32;
    const short* vb = qb + (size_t)32 * MP * 32;

    // q/k fragments for S^T = K @ Q^T (A = K: row j; B = Q^T: col i; k = d)
    s16x8 qf[2][2], kf[2][2];
#pragma unroll
    for (int t = 0; t < 2; t++) {
        int row = t * 32 + l31;
#pragma unroll
        for (int s = 0; s < 2; s++) {
            qf[t][s] = *(const s16x8*)(qb + row * 32 + 16 * s + 8 * h);
            kf[t][s] = *(const s16x8*)(kb + row * 32 + 16 * s + 8 * h);
        }
    }

    // V B-fragments: lane: col d = l31, k-rows j = 16*jc + 8h + e
    // (rows >= 49 read bounded neighbor data, killed by P=0)
    union U8 { short s[8]; s16x8 v; };
    U8 vf[4];
#pragma unroll
    for (int jc = 0; jc < 4; jc++)
#pragma unroll
        for (int e = 0; e < 8; e++)
            vf[jc].s[e] = vb[(16 * jc + 8 * h + e) * 32 + l31];

    // S^T tiles: st[jt][it], elem r: j = 32jt + (r&3)+8(r>>2)+4h, i = 32it + l31
    f32x16 st[2][2] = {};
#pragma unroll
    for (int s = 0; s < 2; s++)
#pragma unroll
        for (int jt = 0; jt < 2; jt++)
#pragma unroll
            for (int it = 0; it < 2; it++)
                st[jt][it] = mfma32(kf[jt][s], qf[it][s], st[jt][it]);

    // + (rel-pos bias + mask), padded j -> -1e30. bmT coalesced over i.
    const float* bs = bmT + ((size_t)((w & 63) * NHEADS + head)) * 3136 + l31;
#pragma unroll
    for (int jt = 0; jt < 2; jt++)
#pragma unroll
        for (int it = 0; it < 2; it++)
#pragma unroll
            for (int r = 0; r < 16; r++) {
                int j = 32 * jt + (r & 3) + 8 * (r >> 2) + 4 * h;
                if (j < 49) st[jt][it][r] += bs[j * 64 + 32 * it];
                else        st[jt][it][r] = -1e30f;
            }

    // softmax over j (per column i): 32 in-lane values + cross-half xor32
    float inv[2];
#pragma unroll
    for (int it = 0; it < 2; it++) {
        float mx = -1e30f;
#pragma unroll
        for (int jt = 0; jt < 2; jt++)
#pragma unroll
            for (int r = 0; r < 16; r++) mx = fmaxf(mx, st[jt][it][r]);
        mx = fmaxf(mx, __shfl_xor(mx, 32));
        float sum = 0.f;
#pragma unroll
        for (int jt = 0; jt < 2; jt++)
#pragma unroll
            for (int r = 0; r < 16; r++) {
                float e = __expf(st[jt][it][r] - mx);
                st[jt][it][r] = e;
                sum += e;
            }
        sum += __shfl_xor(sum, 32);
        inv[it] = 1.0f / sum;
    }

    // PV: P A-frags built in-register (cvt_pk + shfl_xor(32) cross-half fetch)
    f32x16 oacc[2] = {};
#pragma unroll
    for (int jc = 0; jc < 4; jc++) {
        const int jt = jc >> 1, rb = 8 * (jc & 1);
#pragma unroll
        for (int it = 0; it < 2; it++) {
            float iv = inv[it];
            unsigned pk0  = cvtpk(st[jt][it][rb + 0] * iv, st[jt][it][rb + 1] * iv);
            unsigned pk0b = cvtpk(st[jt][it][rb + 2] * iv, st[jt][it][rb + 3] * iv);
            unsigned pk1  = cvtpk(st[jt][it][rb + 4] * iv, st[jt][it][rb + 5] * iv);
            unsigned pk1b = cvtpk(st[jt][it][rb + 6] * iv, st[jt][it][rb + 7] * iv);
            unsigned o0  = __shfl_xor(pk0, 32);
            unsigned o0b = __shfl_xor(pk0b, 32);
            unsigned o1  = __shfl_xor(pk1, 32);
            unsigned o1b = __shfl_xor(pk1b, 32);
            union { unsigned d[4]; s16x8 v; } pa;
            pa.d[0] = h ? o1  : pk0;
            pa.d[1] = h ? o1b : pk0b;
            pa.d[2] = h ? pk1 : o0;
            pa.d[3] = h ? pk1b : o0b;
            oacc[it] = mfma32(pa.v, vf[jc].v, oacc[it]);
        }
    }

    // store: col d = l31, row i = 32it + 4h + (r&3) + 8(r>>2)
    short* ob = ao + (size_t)w * 49 * 512 + head * 32 + l31;
#pragma unroll
    for (int it = 0; it < 2; it++)
#pragma unroll
        for (int r = 0; r < 16; r++) {
            int i = 32 * it + 4 * h + (r & 3) + 8 * (r >> 2);
            if (i < 49) ob[(size_t)i * 512] = f2bf(oacc[it][r]);
        }
}

// ---------------- launch ----------------

extern "C" void kernel_launch(void* const* d_in, const int* in_sizes, int n_in,
                              void* d_out, int out_size, void* d_ws, size_t ws_size,
                              hipStream_t stream) {
    const float* x     = (const float*)d_in[0];
    const float* mask  = (const float*)d_in[1];
    const float* Wqkv  = (const float*)d_in[2];
    const float* bqkv  = (const float*)d_in[3];
    const float* btab  = (const float*)d_in[4];
    const float* Wproj = (const float*)d_in[5];
    const float* bproj = (const float*)d_in[6];
    float* out = (float*)d_out;

    char* ws = (char*)d_ws;
    size_t off = 0;
    short* xb     = (short*)(ws + off); off += (size_t)M_TOTAL * 512 * 2;          // reused as ao
    short* qkvb   = (short*)(ws + off); off += (size_t)48 * M_TOTAL * 32 * 2 + 65536;  // head-major + pad
    short* Wqkvb  = (short*)(ws + off); off += (size_t)1536 * 512 * 2;
    short* Wprojb = (short*)(ws + off); off += (size_t)512 * 512 * 2;
    float* bmT    = (float*)(ws + off); off += (size_t)64 * NHEADS * 49 * 64 * 4;  // 12.85 MB
    short* ao = xb;   // alias: xb dead after qkv GEMM

    k_prep_x<<<2048, 256, 0, stream>>>(x, xb);
    k_prep_w<<<1536, 256, 0, stream>>>(Wqkv, Wqkvb, 1536 * 512, 512 * 512);
    k_prep_w<<<512, 256, 0, stream>>>(Wproj, Wprojb, 512 * 512, 0);
    k_prep_bm<<<2048, 256, 0, stream>>>(btab, mask, bmT);

    k_gemm<0><<<4704, 512, 0, stream>>>(xb, Wqkvb, bqkv, qkvb, 6, 4704);
    k_attn<<<16384, 256, 0, stream>>>(qkvb, bmT, ao);
    k_gemm<1><<<1568, 512, 0, stream>>>(ao, Wprojb, bproj, out, 2, 1568);
}

// Round 7
// 1153.299 us; speedup vs baseline: 1.3040x; 1.0094x over previous
//
#include <hip/hip_runtime.h>
#include <stdint.h>

#define NHEADS 16
#define DIM 512
#define BWIN 4096
#define NTOK 49
#define M_TOTAL (BWIN * NTOK)          // 200704 = 784 * 256
#define QSCALE 0.17677669529663687f    // 32^-0.5

typedef __attribute__((ext_vector_type(4)))  float f32x4;
typedef __attribute__((ext_vector_type(16))) float f32x16;
typedef __attribute__((ext_vector_type(8)))  short s16x8;
typedef __attribute__((ext_vector_type(4)))  short s16x4;

__device__ __forceinline__ f32x16 mfma32(s16x8 a, s16x8 b, f32x16 c) {
    return __builtin_amdgcn_mfma_f32_32x32x16_bf16(a, b, c, 0, 0, 0);
}

// f32 -> bf16 round-nearest-even
__device__ __forceinline__ short f2bf(float f) {
    unsigned u = __builtin_bit_cast(unsigned, f);
    u += 0x7FFFu + ((u >> 16) & 1u);
    return (short)(u >> 16);
}

// pack two f32 -> 2x bf16 in one dword (lo = a, hi = b)
__device__ __forceinline__ unsigned cvtpk(float a, float b) {
    unsigned r;
    asm("v_cvt_pk_bf16_f32 %0, %1, %2" : "=v"(r) : "v"(a), "v"(b));
    return r;
}

__device__ __forceinline__ void gload16(const void* g, void* l) {
    __builtin_amdgcn_global_load_lds(
        (const __attribute__((address_space(1))) void*)g,
        (__attribute__((address_space(3))) void*)l, 16, 0, 0);
}

// ---------------- prep kernels ----------------

__global__ void k_prep_w(const float* __restrict__ src, short* __restrict__ dst,
                         int n, int scale_lim) {
    int i = blockIdx.x * blockDim.x + threadIdx.x;
    int stride = gridDim.x * blockDim.x;
    for (; i < n; i += stride) {
        float v = src[i];
        if (i < scale_lim) v *= QSCALE;
        dst[i] = f2bf(v);
    }
}

// bmT[w64][h][j][i64] = bias_table[rel(i,j)*16+h] + mask[w64][i*49+j]   (i padded to 64)
__global__ void k_prep_bm(const float* __restrict__ btab, const float* __restrict__ mask,
                          float* __restrict__ bmT) {
    int idx = blockIdx.x * blockDim.x + threadIdx.x;
    int stride = gridDim.x * blockDim.x;
    const int n = 64 * NHEADS * 49 * 64;
    for (; idx < n; idx += stride) {
        int i = idx & 63;
        int rest = idx >> 6;
        int j = rest % 49;
        int wh = rest / 49;
        int head = wh & 15;
        int w64 = wh >> 4;
        float v = 0.f;
        if (i < 49) {
            int ridx = (i / 7 - j / 7 + 6) * 13 + (i % 7 - j % 7 + 6);
            v = btab[ridx * 16 + head] + mask[(w64 * 49 + i) * 49 + j];
        }
        bmT[idx] = v;
    }
}

// ---------------- GEMM: C[M,N] = A[M,512] @ B^T[N,512] + bias ----------------
// 256x256 tile, BK=64, 8 waves (2Mx4N), 32x32x16 MFMA, 4 phases/K-tile,
// ONE barrier per phase, per-phase counted vmcnt + lgkm drain.
// MODE 0: A = x (f32, fused convert via reg-stage: load f32 2 phases ahead,
//         cvt_pk -> swizzled ds_write). B via global_load_lds.
//         C -> bf16 head-major planes [n/32][M][32] via LDS-bounce epilogue.
// MODE 1: A,B bf16 via global_load_lds (r6-proven staging); C -> f32 direct.
template <int MODE>
__global__ __launch_bounds__(512, 2) void k_gemm(
    const float* __restrict__ Af, const short* __restrict__ Ab,
    const short* __restrict__ B,
    const float* __restrict__ bias, void* __restrict__ C,
    int ntiles, int nwg) {
    __shared__ short lA[2][256 * 64];   // 64 KB
    __shared__ short lB[2][256 * 64];   // 64 KB
    const int K = 512;
    const size_t MP = M_TOTAL;

    int bid   = blockIdx.x;
    int chunk = nwg >> 3;                      // nwg % 8 == 0
    int wg    = (bid & 7) * chunk + (bid >> 3);
    int mt = wg / ntiles;
    int nt = wg - mt * ntiles;

    int t = threadIdx.x;
    int lane = t & 63, wid = t >> 6;
    int l31 = lane & 31, h = lane >> 5;
    int wr = wid >> 2, wc = wid & 3;           // wave tile: rows wr*128, cols wc*64
    int wslot = (t & 7) ^ ((t >> 3) & 7);      // fixed swizzled 16B slot for staging

    const short* aTb = Ab + (size_t)mt * 256 * K;   // MODE1 A source (bf16)
    const float* aTf = Af + (size_t)mt * 256 * K;   // MODE0 A source (f32)
    const short* bT  = B  + (size_t)nt * 256 * K;

    f32x16 acc[4][2] = {};
    s16x8 afr[2][4], bfr[4];
    f32x4 cqa0, cqa1, cqb0, cqb1, lqa0, lqa1, lqb0, lqb1;

// ---- staging macros (A bf16 by row-bit6 halves; B by row-bit5 halves) ----
#define STAGE_A(buf, H, kt) do {                                               \
    _Pragma("unroll") for (int j = 0; j < 2; j++) {                            \
        int r_ = j * 128 + (H) * 64 + (t >> 3);                                \
        int sc_ = (t & 7) ^ (r_ & 7);                                          \
        gload16(aTb + (size_t)r_ * K + (kt) * 64 + sc_ * 8,                    \
                &lA[buf][r_ * 64 + (t & 7) * 8]);                              \
    } } while (0)

#define STAGE_B(buf, H, kt) do {                                               \
    _Pragma("unroll") for (int j = 0; j < 2; j++) {                            \
        int u_ = j * 64 + (t >> 3);                                            \
        int r_ = ((u_ >> 5) << 6) | ((H) << 5) | (u_ & 31);                    \
        int sc_ = (t & 7) ^ (r_ & 7);                                          \
        gload16(bT + (size_t)r_ * K + (kt) * 64 + sc_ * 8,                     \
                &lB[buf][r_ * 64 + (t & 7) * 8]);                              \
    } } while (0)

// ---- MODE0 A reg-staging: load 2xf32x4, later cvt+swizzled ds_write ----
#define LOADA(rb, kt2, r0, r1) do {                                            \
    const float* ps_ = aTf + ((size_t)((rb) + (t >> 3))) * K + (kt2) * 64 +    \
                       (t & 7) * 8;                                            \
    r0 = *(const f32x4*)ps_; r1 = *(const f32x4*)(ps_ + 4); } while (0)

#define WRA(buf, rb, r0, r1) do {                                              \
    union { unsigned d[4]; s16x8 v; } u_;                                      \
    u_.d[0] = cvtpk(r0[0], r0[1]); u_.d[1] = cvtpk(r0[2], r0[3]);              \
    u_.d[2] = cvtpk(r1[0], r1[1]); u_.d[3] = cvtpk(r1[2], r1[3]);              \
    *(s16x8*)(&lA[buf][((rb) + (t >> 3)) * 64 + wslot * 8]) = u_.v; } while (0)

// ---- 32x32x16 fragment reads (XOR-swizzled b128) ----
#define LDA32(AH, cur) do {                                                    \
    const short* pa_ = &lA[cur][(wr * 128 + (AH) * 64 + l31) * 64];            \
    _Pragma("unroll") for (int a2 = 0; a2 < 2; a2++)                           \
    _Pragma("unroll") for (int ks = 0; ks < 4; ks++)                           \
        afr[a2][ks] = *(const s16x8*)(pa_ + a2 * 2048 +                        \
                                      (((ks * 2 + h) ^ (l31 & 7)) * 8));       \
    } while (0)

#define LDB32(BH, cur) do {                                                    \
    const short* pb_ = &lB[cur][(wc * 64 + (BH) * 32 + l31) * 64];             \
    _Pragma("unroll") for (int ks = 0; ks < 4; ks++)                           \
        bfr[ks] = *(const s16x8*)(pb_ + (((ks * 2 + h) ^ (l31 & 7)) * 8));     \
    } while (0)

#define MMQ32(AH, BH) do {                                                     \
    __builtin_amdgcn_s_setprio(1);                                             \
    _Pragma("unroll") for (int ks = 0; ks < 4; ks++)                           \
    _Pragma("unroll") for (int a2 = 0; a2 < 2; a2++)                           \
        acc[(AH) * 2 + a2][BH] =                                               \
            mfma32(afr[a2][ks], bfr[ks], acc[(AH) * 2 + a2][BH]);              \
    __builtin_amdgcn_s_setprio(0);                                             \
} while (0)

#define PWAIT(s) do {                                                          \
    if (s) { if (MODE == 0)                                                    \
                 asm volatile("s_waitcnt vmcnt(6) lgkmcnt(0)" ::: "memory");   \
             else                                                              \
                 asm volatile("s_waitcnt vmcnt(4) lgkmcnt(0)" ::: "memory"); } \
    else asm volatile("s_waitcnt vmcnt(0) lgkmcnt(0)" ::: "memory");           \
} while (0)

#define BARP() do { __builtin_amdgcn_s_barrier();                              \
                    __builtin_amdgcn_sched_barrier(0); } while (0)

    // -------- prologue: stage tile 0, prime tile-1 A carries --------
    if constexpr (MODE == 0) {
        STAGE_B(0, 0, 0); STAGE_B(0, 1, 0);
#pragma unroll
        for (int c = 0; c < 4; c++) {
            int rb = (c & 1) * 128 + (c >> 1) * 64;  // {0,128,64,192}
            f32x4 ta, tb;
            LOADA(rb, 0, ta, tb);
            WRA(0, rb, ta, tb);
        }
        LOADA(0,   1, cqa0, cqa1);   // q0a of tile 1
        LOADA(128, 1, cqb0, cqb1);   // q0b of tile 1
        asm volatile("s_waitcnt vmcnt(4) lgkmcnt(0)" ::: "memory");
    } else {
        STAGE_A(0, 0, 0); STAGE_B(0, 0, 0);
        STAGE_B(0, 1, 0); STAGE_A(0, 1, 0);
        asm volatile("s_waitcnt vmcnt(0) lgkmcnt(0)" ::: "memory");
    }
    BARP();

    for (int kt = 0; kt < 8; ++kt) {
        const int cur = kt & 1, nxt = cur ^ 1;
        const bool s7 = kt < 7, s6 = kt < 6;
        // ---- phase 1: Q(A0,B0); stage B-h0 / write q0a / load q1a
        LDA32(0, cur); LDB32(0, cur);
        if constexpr (MODE == 0) {
            if (s7) {
                STAGE_B(nxt, 0, kt + 1);
                LOADA(64, kt + 1, lqa0, lqa1);
                WRA(nxt, 0, cqa0, cqa1);
            }
        } else {
            if (s7) STAGE_A(nxt, 0, kt + 1);
        }
        PWAIT(s7);
        MMQ32(0, 0);
        BARP();
        // ---- phase 2: Q(A0,B1); stage B-h1 / write q0b / load q1b
        LDB32(1, cur);
        if constexpr (MODE == 0) {
            if (s7) {
                STAGE_B(nxt, 1, kt + 1);
                LOADA(192, kt + 1, lqb0, lqb1);
                WRA(nxt, 128, cqb0, cqb1);
            }
        } else {
            if (s7) STAGE_B(nxt, 0, kt + 1);
        }
        PWAIT(s7);
        MMQ32(0, 1);
        BARP();
        // ---- phase 3: Q(A1,B1); load q0a(kt+2) / write q1a
        LDA32(1, cur);
        if constexpr (MODE == 0) {
            if (s6) LOADA(0, kt + 2, cqa0, cqa1);
            if (s7) WRA(nxt, 64, lqa0, lqa1);
        } else {
            if (s7) STAGE_B(nxt, 1, kt + 1);
        }
        PWAIT(s7);
        MMQ32(1, 1);
        BARP();
        // ---- phase 4: Q(A1,B0); load q0b(kt+2) / write q1b
        LDB32(0, cur);                       // re-read B-h0
        if constexpr (MODE == 0) {
            if (s6) LOADA(128, kt + 2, cqb0, cqb1);
            if (s7) WRA(nxt, 192, lqb0, lqb1);
        } else {
            if (s7) STAGE_A(nxt, 1, kt + 1);
        }
        PWAIT(s7);
        MMQ32(1, 0);
        BARP();
    }

#undef STAGE_A
#undef STAGE_B
#undef LOADA
#undef WRA
#undef LDA32
#undef LDB32
#undef MMQ32
#undef PWAIT
#undef BARP

    int m0 = mt * 256 + wr * 128;
    int n0 = nt * 256 + wc * 64;
    // C layout (32x32, verified): row = at*32 + 4h + (r&3) + 8*(r>>2), col = bt*32 + l31
    if constexpr (MODE == 0) {
        // bounce C through dead LDS: per-wave 128x64 bf16 region (16 KB)
        short* region = (wid < 4) ? (&lA[0][0] + wid * 8192)
                                  : (&lB[0][0] + (wid - 4) * 8192);
#pragma unroll
        for (int bt = 0; bt < 2; bt++) {
            int n = n0 + bt * 32 + l31;
            float bv = bias[n];
            if (n < 512) bv *= QSCALE;
            int cchunk = bt * 4 + (l31 >> 3);
#pragma unroll
            for (int at = 0; at < 4; at++)
#pragma unroll
                for (int r = 0; r < 16; r++) {
                    int row = at * 32 + 4 * h + (r & 3) + 8 * (r >> 2);
                    region[row * 64 + ((cchunk ^ (row & 7)) * 8) + (l31 & 7)] =
                        f2bf(acc[at][bt][r] + bv);
                }
        }
        // per-wave private region; compiler inserts lgkmcnt for RAW
#pragma unroll
        for (int p = 0; p < 2; p++) {
            int plane = (n0 >> 5) + p;                   // n/32 = which*16+head
            short* dst = (short*)C + ((size_t)plane * MP + m0) * 32;
#pragma unroll
            for (int i = 0; i < 8; i++) {
                int f = i * 64 + lane;
                int row = f >> 2, c = f & 3;
                s16x8 v = *(const s16x8*)(region + row * 64 +
                                          (((p * 4 + c) ^ (row & 7)) * 8));
                *(s16x8*)(dst + (size_t)f * 8) = v;      // coalesced 16B
            }
        }
    } else {
#pragma unroll
        for (int bt = 0; bt < 2; bt++) {
            int n = n0 + bt * 32 + l31;
            float bv = bias[n];
#pragma unroll
            for (int at = 0; at < 4; at++)
#pragma unroll
                for (int r = 0; r < 16; r++) {
                    int m = m0 + at * 32 + 4 * h + (r & 3) + 8 * (r >> 2);
                    ((float*)C)[(size_t)m * 512 + n] = acc[at][bt][r] + bv;
                }
        }
    }
}

// ---------------- attention (LDS-free, 32x32 MFMA + shfl P-transpose) --------
// qkv head-major: [which][head][MP][32]. One wave per (window, head).
__global__ __launch_bounds__(256, 4) void k_attn(
    const short* __restrict__ qkv, const float* __restrict__ bmT,
    short* __restrict__ ao) {
    int wid = threadIdx.x >> 6, lane = threadIdx.x & 63;
    int p = blockIdx.x * 4 + wid;
    int w = p >> 4, head = p & 15;
    int l31 = lane & 31, h = lane >> 5;
    const size_t MP = M_TOTAL;

    const short* qb = qkv + ((size_t)head * MP + w * 49) * 32;
    const short* kb = qb + (size_t)16 * MP * 32;
    const short* vb = qb + (size_t)32 * MP * 32;

    // q/k fragments for S^T = K @ Q^T (A = K: row j; B = Q^T: col i; k = d)
    s16x8 qf[2][2], kf[2][2];
#pragma unroll
    for (int t = 0; t < 2; t++) {
        int row = t * 32 + l31;
#pragma unroll
        for (int s = 0; s < 2; s++) {
            qf[t][s] = *(const s16x8*)(qb + row * 32 + 16 * s + 8 * h);
            kf[t][s] = *(const s16x8*)(kb + row * 32 + 16 * s + 8 * h);
        }
    }

    // V B-fragments: lane: col d = l31, k-rows j = 16*jc + 8h + e
    union U8 { short s[8]; s16x8 v; };
    U8 vf[4];
#pragma unroll
    for (int jc = 0; jc < 4; jc++)
#pragma unroll
        for (int e = 0; e < 8; e++)
            vf[jc].s[e] = vb[(16 * jc + 8 * h + e) * 32 + l31];

    // S^T tiles: st[jt][it], elem r: j = 32jt + (r&3)+8(r>>2)+4h, i = 32it + l31
    f32x16 st[2][2] = {};
#pragma unroll
    for (int s = 0; s < 2; s++)
#pragma unroll
        for (int jt = 0; jt < 2; jt++)
#pragma unroll
            for (int it = 0; it < 2; it++)
                st[jt][it] = mfma32(kf[jt][s], qf[it][s], st[jt][it]);

    // + (rel-pos bias + mask), padded j -> -1e30. bmT coalesced over i.
    const float* bs = bmT + ((size_t)((w & 63) * NHEADS + head)) * 3136 + l31;
#pragma unroll
    for (int jt = 0; jt < 2; jt++)
#pragma unroll
        for (int it = 0; it < 2; it++)
#pragma unroll
            for (int r = 0; r < 16; r++) {
                int j = 32 * jt + (r & 3) + 8 * (r >> 2) + 4 * h;
                if (j < 49) st[jt][it][r] += bs[j * 64 + 32 * it];
                else        st[jt][it][r] = -1e30f;
            }

    // softmax over j (per column i): 32 in-lane values + cross-half xor32
    float inv[2];
#pragma unroll
    for (int it = 0; it < 2; it++) {
        float mx = -1e30f;
#pragma unroll
        for (int jt = 0; jt < 2; jt++)
#pragma unroll
            for (int r = 0; r < 16; r++) mx = fmaxf(mx, st[jt][it][r]);
        mx = fmaxf(mx, __shfl_xor(mx, 32));
        float sum = 0.f;
#pragma unroll
        for (int jt = 0; jt < 2; jt++)
#pragma unroll
            for (int r = 0; r < 16; r++) {
                float e = __expf(st[jt][it][r] - mx);
                st[jt][it][r] = e;
                sum += e;
            }
        sum += __shfl_xor(sum, 32);
        inv[it] = 1.0f / sum;
    }

    // PV: P A-frags built in-register (cvt_pk + shfl_xor(32) cross-half fetch)
    f32x16 oacc[2] = {};
#pragma unroll
    for (int jc = 0; jc < 4; jc++) {
        const int jt = jc >> 1, rb = 8 * (jc & 1);
#pragma unroll
        for (int it = 0; it < 2; it++) {
            float iv = inv[it];
            unsigned pk0  = cvtpk(st[jt][it][rb + 0] * iv, st[jt][it][rb + 1] * iv);
            unsigned pk0b = cvtpk(st[jt][it][rb + 2] * iv, st[jt][it][rb + 3] * iv);
            unsigned pk1  = cvtpk(st[jt][it][rb + 4] * iv, st[jt][it][rb + 5] * iv);
            unsigned pk1b = cvtpk(st[jt][it][rb + 6] * iv, st[jt][it][rb + 7] * iv);
            unsigned o0  = __shfl_xor(pk0, 32);
            unsigned o0b = __shfl_xor(pk0b, 32);
            unsigned o1  = __shfl_xor(pk1, 32);
            unsigned o1b = __shfl_xor(pk1b, 32);
            union { unsigned d[4]; s16x8 v; } pa;
            pa.d[0] = h ? o1  : pk0;
            pa.d[1] = h ? o1b : pk0b;
            pa.d[2] = h ? pk1 : o0;
            pa.d[3] = h ? pk1b : o0b;
            oacc[it] = mfma32(pa.v, vf[jc].v, oacc[it]);
        }
    }

    // store: col d = l31, row i = 32it + 4h + (r&3) + 8(r>>2)
    short* ob = ao + (size_t)w * 49 * 512 + head * 32 + l31;
#pragma unroll
    for (int it = 0; it < 2; it++)
#pragma unroll
        for (int r = 0; r < 16; r++) {
            int i = 32 * it + 4 * h + (r & 3) + 8 * (r >> 2);
            if (i < 49) ob[(size_t)i * 512] = f2bf(oacc[it][r]);
        }
}

// ---------------- launch ----------------

extern "C" void kernel_launch(void* const* d_in, const int* in_sizes, int n_in,
                              void* d_out, int out_size, void* d_ws, size_t ws_size,
                              hipStream_t stream) {
    const float* x     = (const float*)d_in[0];
    const float* mask  = (const float*)d_in[1];
    const float* Wqkv  = (const float*)d_in[2];
    const float* bqkv  = (const float*)d_in[3];
    const float* btab  = (const float*)d_in[4];
    const float* Wproj = (const float*)d_in[5];
    const float* bproj = (const float*)d_in[6];
    float* out = (float*)d_out;

    char* ws = (char*)d_ws;
    size_t off = 0;
    short* ao     = (short*)(ws + off); off += (size_t)M_TOTAL * 512 * 2;
    short* qkvb   = (short*)(ws + off); off += (size_t)48 * M_TOTAL * 32 * 2 + 65536;
    short* Wqkvb  = (short*)(ws + off); off += (size_t)1536 * 512 * 2;
    short* Wprojb = (short*)(ws + off); off += (size_t)512 * 512 * 2;
    float* bmT    = (float*)(ws + off); off += (size_t)64 * NHEADS * 49 * 64 * 4;

    k_prep_w<<<1536, 256, 0, stream>>>(Wqkv, Wqkvb, 1536 * 512, 512 * 512);
    k_prep_w<<<512, 256, 0, stream>>>(Wproj, Wprojb, 512 * 512, 0);
    k_prep_bm<<<2048, 256, 0, stream>>>(btab, mask, bmT);

    k_gemm<0><<<4704, 512, 0, stream>>>(x, nullptr, Wqkvb, bqkv, qkvb, 6, 4704);
    k_attn<<<16384, 256, 0, stream>>>(qkvb, bmT, ao);
    k_gemm<1><<<1568, 512, 0, stream>>>(nullptr, ao, Wprojb, bproj, out, 2, 1568);
}